// Round 8
// baseline (76507.141 us; speedup 1.0000x reference)
//
#include <hip/hip_runtime.h>

typedef _Float16 half_t;
typedef _Float16 half8 __attribute__((ext_vector_type(8)));
typedef float floatx4 __attribute__((ext_vector_type(4)));
typedef int int4v __attribute__((ext_vector_type(4)));

#define NSTEP 512
#define INV2048 (1.0f / 2048.0f)

// hi/lo blobs: [layer(2)][wg(256)][wv(4)][kk(16)][lane(64)][i(8)] f16
// A-frag: mloc = lane&15 -> gate = mloc>>2, unit u = mloc&3; grow = gate*1024 + wg*4 + u
// k = wv*512 + kk*32 + (lane>>4)*8 + i;  k<1024 -> W_ih else W_hh
__global__ void conv_w(const float* __restrict__ Wih, const float* __restrict__ Whh,
                       half_t* __restrict__ whi, half_t* __restrict__ wlo) {
  long e = (long)blockIdx.x * 256 + threadIdx.x;  // 2^24 elements
  int lane = (int)((e >> 3) & 63);
  int kk   = (int)((e >> 9) & 15);
  int wv   = (int)((e >> 13) & 3);
  int wg   = (int)((e >> 15) & 255);
  int layer = (int)(e >> 23);
  int i    = (int)(e & 7);
  int mloc = lane & 15;
  int grow = (mloc >> 2) * 1024 + wg * 4 + (mloc & 3);
  int k = wv * 512 + kk * 32 + ((lane >> 4) * 8) + i;
  long base = ((long)layer << 22) + (long)grow * 1024;
  float v = (k < 1024) ? Wih[base + k] : Whh[base + (k - 1024)];
  half_t hi = (half_t)v;
  whi[e] = hi;
  wlo[e] = (half_t)((v - (float)hi) * 2048.0f);
}

__global__ void init_bar(int* bar) { *bar = 0; }

__device__ __forceinline__ float sigm(float x) { return 1.f / (1.f + __expf(-x)); }
__device__ __forceinline__ float tanh_f(float x) {
  x = fminf(15.f, fmaxf(-15.f, x));
  float e = __expf(-2.f * x);
  return (1.f - e) / (1.f + e);
}

__device__ __forceinline__ void gbar(int* bar, int target) {
  __syncthreads();
  if (threadIdx.x == 0) {
    __hip_atomic_fetch_add(bar, 1, __ATOMIC_RELEASE, __HIP_MEMORY_SCOPE_AGENT);
    while (__hip_atomic_load(bar, __ATOMIC_ACQUIRE, __HIP_MEMORY_SCOPE_AGENT) < target)
      __builtin_amdgcn_s_sleep(16);
  }
  __syncthreads();
}

// 512 WGs x 256 thr, 2 WGs/CU. WGs [0,256): layer 1 step t=p; [256,512): layer 2 step t=p-1.
// Each WG: 4 units (16 gate rows), K=2048 over 4 waves (wv<2: x-part, wv>=2: h-part).
// hi-weights in LDS (64 KB, staged once); lo residual streamed from L3 each phase.
__launch_bounds__(256, 2)
__global__ void lstm_main(const int* __restrict__ tokens, const float* __restrict__ emb,
                          const float* __restrict__ bih, const float* __restrict__ bhh,
                          const half_t* __restrict__ whi, const half_t* __restrict__ wlo,
                          half_t* __restrict__ h1hi, half_t* __restrict__ h1lo,
                          half_t* __restrict__ h2hi, half_t* __restrict__ h2lo,
                          int* __restrict__ bar, float* __restrict__ out) {
  __shared__ half_t wlds[4][16][64][8];  // 64 KB
  __shared__ float part[4][16][64];      // 16 KB  -> 80 KB total, 2 WGs/CU
  const int wgid = blockIdx.x;
  const int layer = wgid >> 8;
  const int wg = wgid & 255;
  const int tid = (int)threadIdx.x;
  const int wv = tid >> 6;
  const int lane = tid & 63;

  // stage hi weights: 64 KB global -> LDS, once
  {
    const int4v* src = (const int4v*)(whi + ((long)(layer * 256 + wg)) * 32768);
    int4v* dst = (int4v*)&wlds[0][0][0][0];
    #pragma unroll
    for (int it = 0; it < 16; ++it) dst[it * 256 + tid] = src[it * 256 + tid];
  }
  const half_t* lostream = wlo + ((long)(layer * 256 + wg)) * 32768 + wv * 8192;

  float bsum[4];
  {
    int u = tid & 3;
    for (int g = 0; g < 4; ++g) {
      int bi = layer * 4096 + g * 1024 + wg * 4 + u;
      bsum[g] = bih[bi] + bhh[bi];
    }
  }
  float c = 0.f;
  __syncthreads();

  for (int p = 0; p <= NSTEP; ++p) {
    const bool active = (layer == 0) ? (p < NSTEP) : (p >= 1);
    const int t = (layer == 0) ? p : (p - 1);
    floatx4 zero = {0.f, 0.f, 0.f, 0.f};
    floatx4 acc_h[4], acc_l[4];
    #pragma unroll
    for (int b = 0; b < 4; ++b) { acc_h[b] = zero; acc_l[b] = zero; }

    if (active) {
      const bool skipH = (wv >= 2) && (t == 0);  // h_{t-1}=0 at t==0
      if (!skipH) {
        if (layer == 0 && wv < 2) {
          // x-part from f32 embedding (token 0 -> zero row), split hi/lo on the fly
          int tk[4];
          #pragma unroll
          for (int nt = 0; nt < 4; ++nt) tk[nt] = tokens[t * 64 + nt * 16 + (lane & 15)];
          #pragma unroll 2
          for (int kk = 0; kk < 16; ++kk) {
            half8 ah = *(const half8*)&wlds[wv][kk][lane][0];
            half8 al = *(const half8*)(lostream + kk * 512 + lane * 8);
            int kb = wv * 512 + kk * 32 + ((lane >> 4) * 8);
            #pragma unroll
            for (int nt = 0; nt < 4; ++nt) {
              int tok = tk[nt];
              const float* src = emb + (long)tok * 1024 + kb;
              floatx4 x0 = *(const floatx4*)(src);
              floatx4 x1 = *(const floatx4*)(src + 4);
              float msk = (tok == 0) ? 0.f : 1.f;
              half8 bh, bl;
              #pragma unroll
              for (int q = 0; q < 4; ++q) {
                float v0 = x0[q] * msk;
                float v1 = x1[q] * msk;
                half_t h0 = (half_t)v0, h1v = (half_t)v1;
                bh[q] = h0;     bh[q + 4] = h1v;
                bl[q] = (half_t)((v0 - (float)h0) * 2048.f);
                bl[q + 4] = (half_t)((v1 - (float)h1v) * 2048.f);
              }
              acc_h[nt] = __builtin_amdgcn_mfma_f32_16x16x32_f16(ah, bh, acc_h[nt], 0, 0, 0);
              acc_l[nt] = __builtin_amdgcn_mfma_f32_16x16x32_f16(ah, bl, acc_l[nt], 0, 0, 0);
              acc_l[nt] = __builtin_amdgcn_mfma_f32_16x16x32_f16(al, bh, acc_l[nt], 0, 0, 0);
            }
          }
        } else {
          const half_t *abh, *abl;
          int kofs;
          if (wv < 2) {  // layer==1 x-part = h1 at t
            abh = h1hi + ((p - 1) & 1) * 65536;
            abl = h1lo + ((p - 1) & 1) * 65536;
            kofs = wv * 512;
          } else {       // recurrent h-part (own layer)
            abh = (layer == 0 ? h1hi : h2hi) + ((p - 1) & 1) * 65536;
            abl = (layer == 0 ? h1lo : h2lo) + ((p - 1) & 1) * 65536;
            kofs = (wv - 2) * 512;
          }
          #pragma unroll 2
          for (int kk = 0; kk < 16; ++kk) {
            half8 ah = *(const half8*)&wlds[wv][kk][lane][0];
            half8 al = *(const half8*)(lostream + kk * 512 + lane * 8);
            int kb = kofs + kk * 32 + ((lane >> 4) * 8);
            #pragma unroll
            for (int nt = 0; nt < 4; ++nt) {
              int n = nt * 16 + (lane & 15);
              half8 bh = *(const half8*)(abh + n * 1024 + kb);
              half8 bl = *(const half8*)(abl + n * 1024 + kb);
              acc_h[nt] = __builtin_amdgcn_mfma_f32_16x16x32_f16(ah, bh, acc_h[nt], 0, 0, 0);
              acc_l[nt] = __builtin_amdgcn_mfma_f32_16x16x32_f16(ah, bl, acc_l[nt], 0, 0, 0);
              acc_l[nt] = __builtin_amdgcn_mfma_f32_16x16x32_f16(al, bh, acc_l[nt], 0, 0, 0);
            }
          }
        }
      }
      // D frag -> part: row = (lane>>4)*4+q (16 gate rows), col = nt*16 + (lane&15)
      #pragma unroll
      for (int nt = 0; nt < 4; ++nt)
        #pragma unroll
        for (int q = 0; q < 4; ++q)
          part[wv][(lane >> 4) * 4 + q][nt * 16 + (lane & 15)] =
              acc_h[nt][q] + INV2048 * acc_l[nt][q];
    }
    __syncthreads();
    if (active) {
      int u = tid & 3, n = tid >> 2;
      float s0 = part[0][u][n]      + part[1][u][n]      + part[2][u][n]      + part[3][u][n]      + bsum[0];
      float s1 = part[0][4 + u][n]  + part[1][4 + u][n]  + part[2][4 + u][n]  + part[3][4 + u][n]  + bsum[1];
      float s2 = part[0][8 + u][n]  + part[1][8 + u][n]  + part[2][8 + u][n]  + part[3][8 + u][n]  + bsum[2];
      float s3 = part[0][12 + u][n] + part[1][12 + u][n] + part[2][12 + u][n] + part[3][12 + u][n] + bsum[3];
      float is = sigm(s0), fs = sigm(s1), gt = tanh_f(s2), os = sigm(s3);
      c = fs * c + is * gt;
      float h = os * tanh_f(c);
      half_t hhi = (half_t)h;
      half_t* hbh = (layer == 0 ? h1hi : h2hi) + (p & 1) * 65536;
      half_t* hbl = (layer == 0 ? h1lo : h2lo) + (p & 1) * 65536;
      hbh[n * 1024 + wg * 4 + u] = hhi;
      hbl[n * 1024 + wg * 4 + u] = (half_t)((h - (float)hhi) * 2048.f);
      if (layer == 1)
        __builtin_nontemporal_store(h, &out[((long)t * 64 + n) * 1024 + wg * 4 + u]);
    }
    __builtin_amdgcn_fence(__ATOMIC_RELEASE, "agent");
    gbar(bar, 512 * (p + 1));
    __builtin_amdgcn_fence(__ATOMIC_ACQUIRE, "agent");
  }
}

extern "C" void kernel_launch(void* const* d_in, const int* in_sizes, int n_in,
                              void* d_out, int out_size, void* d_ws, size_t ws_size,
                              hipStream_t stream) {
  const int*   tokens = (const int*)d_in[0];
  const float* emb    = (const float*)d_in[1];
  const float* Wih    = (const float*)d_in[2];
  const float* Whh    = (const float*)d_in[3];
  const float* bih    = (const float*)d_in[4];
  const float* bhh    = (const float*)d_in[5];
  float* out = (float*)d_out;  // reference output dtype is float32

  half_t* whi = (half_t*)d_ws;                               // 33,554,432 B
  half_t* wlo = (half_t*)((char*)d_ws + 33554432);           // 33,554,432 B
  char* hb = (char*)d_ws + 67108864;
  half_t* h1hi = (half_t*)(hb);
  half_t* h1lo = (half_t*)(hb + 262144);
  half_t* h2hi = (half_t*)(hb + 524288);
  half_t* h2lo = (half_t*)(hb + 786432);
  int* bar = (int*)(hb + 1048576);

  hipLaunchKernelGGL(conv_w, dim3(65536), dim3(256), 0, stream, Wih, Whh, whi, wlo);
  hipLaunchKernelGGL(init_bar, dim3(1), dim3(1), 0, stream, bar);

  void* args[] = {(void*)&tokens, (void*)&emb, (void*)&bih, (void*)&bhh,
                  (void*)&whi, (void*)&wlo, (void*)&h1hi, (void*)&h1lo,
                  (void*)&h2hi, (void*)&h2lo, (void*)&bar, (void*)&out};
  hipError_t e = hipLaunchCooperativeKernel((const void*)lstm_main, dim3(512), dim3(256),
                                            args, 0, stream);
  if (e != hipSuccess) {  // signature ~195: cooperative launch refused (resources)
    hipMemsetAsync(d_out, 0x43, (size_t)out_size * 4, stream);
  }
}

// Round 9
// 39735.757 us; speedup vs baseline: 1.9254x; 1.9254x over previous
//
#include <hip/hip_runtime.h>

typedef _Float16 half_t;
typedef _Float16 half8 __attribute__((ext_vector_type(8)));
typedef float floatx4 __attribute__((ext_vector_type(4)));
typedef int int4v __attribute__((ext_vector_type(4)));
typedef unsigned char uchar;

#define NSTEP 512
#define INV2048 (1.0f / 2048.0f)

// ---- fp8 e4m3fn codec (FTZ below 2^-6; decode is shift-only) ----
__device__ __forceinline__ uchar enc_e4m3(float x) {
  unsigned s = (__builtin_bit_cast(unsigned, x) >> 31) & 1u;
  float a = fabsf(x);
  if (a < 0.015625f) return (uchar)(s << 7);  // FTZ (error <= 2^-6 in lo units)
  int E; float m = frexpf(a, &E);             // a = m*2^E, m in [0.5,1)
  int Ee = E - 1;
  int mant = (int)roundf((2.f * m - 1.f) * 8.f);
  if (mant == 8) { Ee++; mant = 0; }
  if (Ee > 8) { Ee = 8; mant = 6; }           // clamp to 448
  return (uchar)((s << 7) | ((Ee + 7) << 3) | mant);
}

__device__ __forceinline__ half8 dec8(unsigned w0, unsigned w1) {
  half8 r;
  #pragma unroll
  for (int j = 0; j < 8; ++j) {
    unsigned b = ((j < 4 ? w0 : w1) >> (8 * (j & 3))) & 0xffu;
    unsigned p = b & 0x7fu;
    unsigned h = (p ? ((p << 7) + 0x2000u) : 0u) | ((b & 0x80u) << 8);
    unsigned short us = (unsigned short)h;
    r[j] = __builtin_bit_cast(half_t, us);
  }
  return r;
}

// hi blob: [layer(2)][wg(128)][wv(4)][frag(32)][lane(64)][i(8)] f16 (32 MB)
// lo blob: same index space, fp8 e4m3 of (v-hi)*2048 (16 MB)
// frag = kk*2+mt; A-row mloc = mt*16+(lane&15) -> gate = mloc>>3, u = mloc&7;
// grow = gate*1024 + wg*8 + u; k = wv*512 + kk*32 + (lane>>4)*8 + i; k<1024 Wih else Whh.
__global__ void conv_w(const float* __restrict__ Wih, const float* __restrict__ Whh,
                       half_t* __restrict__ whi, uchar* __restrict__ wlo) {
  long e = (long)blockIdx.x * 256 + threadIdx.x;  // 2^24
  int i    = (int)(e & 7);
  int lane = (int)((e >> 3) & 63);
  int frag = (int)((e >> 9) & 31);
  int wv   = (int)((e >> 14) & 3);
  int wg   = (int)((e >> 16) & 127);
  int layer = (int)(e >> 23);
  int mt = frag & 1, kk = frag >> 1;
  int mloc = mt * 16 + (lane & 15);
  int grow = (mloc >> 3) * 1024 + wg * 8 + (mloc & 7);
  int k = wv * 512 + kk * 32 + ((lane >> 4) * 8) + i;
  long base = ((long)layer << 22) + (long)grow * 1024;
  float v = (k < 1024) ? Wih[base + k] : Whh[base + (k - 1024)];
  half_t hi = (half_t)v;
  whi[e] = hi;
  wlo[e] = enc_e4m3((v - (float)hi) * 2048.0f);
}

__device__ __forceinline__ float sigm(float x) { return 1.f / (1.f + __expf(-x)); }
__device__ __forceinline__ float tanh_f(float x) {
  x = fminf(15.f, fmaxf(-15.f, x));
  float e = __expf(-2.f * x);
  return (1.f - e) / (1.f + e);
}

// two-level barrier: 16 groups x 16 WGs, padded counters, monotonic
__device__ __forceinline__ void gbar(int* gcnt, int* root, int* gdone, int p) {
  __syncthreads();
  if (threadIdx.x == 0) {
    int g = (int)blockIdx.x >> 4;
    int a = __hip_atomic_fetch_add(&gcnt[g * 64], 1, __ATOMIC_ACQ_REL, __HIP_MEMORY_SCOPE_AGENT);
    if (a == 16 * (p + 1) - 1) {  // last of group this phase
      __hip_atomic_fetch_add(root, 1, __ATOMIC_ACQ_REL, __HIP_MEMORY_SCOPE_AGENT);
      while (__hip_atomic_load(root, __ATOMIC_ACQUIRE, __HIP_MEMORY_SCOPE_AGENT) < 16 * (p + 1))
        __builtin_amdgcn_s_sleep(2);
      __hip_atomic_store(&gdone[g * 64], p + 1, __ATOMIC_RELEASE, __HIP_MEMORY_SCOPE_AGENT);
    } else {
      while (__hip_atomic_load(&gdone[g * 64], __ATOMIC_ACQUIRE, __HIP_MEMORY_SCOPE_AGENT) < p + 1)
        __builtin_amdgcn_s_sleep(2);
    }
  }
  __syncthreads();
}

// 256 WGs x 256 thr, 1 WG/CU. WGs [0,128): layer 1 step t=p; [128,256): layer 2 step t=p-1.
// Each WG: 8 units (32 gate rows); K=2048 over 4 waves. hi weights LDS-resident (128 KB);
// fp8 lo residual streamed from L2 (2 MB/XCD). Cross-wave reduce via LDS atomicAdd.
__launch_bounds__(256, 1)
__global__ void lstm_main(const int* __restrict__ tokens, const float* __restrict__ emb,
                          const float* __restrict__ bih, const float* __restrict__ bhh,
                          const half_t* __restrict__ whi, const uchar* __restrict__ wlo,
                          half_t* __restrict__ h1hi, half_t* __restrict__ h1lo,
                          half_t* __restrict__ h2hi, half_t* __restrict__ h2lo,
                          int* __restrict__ barblk, float* __restrict__ out) {
  __shared__ half_t wlds[4][32][64][8];  // 128 KB
  __shared__ float part[32][68];         // 8.7 KB, 68-stride: <=2-way banks
  const int wgid = blockIdx.x;
  const int layer = wgid >> 7;
  const int wg = wgid & 127;
  const int tid = (int)threadIdx.x;
  const int wv = tid >> 6;
  const int lane = tid & 63;

  int* gcnt  = barblk;
  int* root  = barblk + 1024;
  int* gdone = barblk + 2048;

  // stage hi weights: 128 KB global -> LDS, once
  {
    const int4v* src = (const int4v*)(whi + (((long)(layer * 128 + wg)) << 16));
    int4v* dst = (int4v*)&wlds[0][0][0][0];
    #pragma unroll
    for (int it = 0; it < 32; ++it) dst[it * 256 + tid] = src[it * 256 + tid];
  }
  const uchar* lob = wlo + ((((long)(layer * 128 + wg)) * 4 + wv) << 14);

  float bsum[4];
  {
    int u = tid & 7;
    for (int g = 0; g < 4; ++g) {
      int bi = layer * 4096 + g * 1024 + wg * 8 + u;
      bsum[g] = bih[bi] + bhh[bi];
    }
  }
  float c0 = 0.f, c1 = 0.f;
  __syncthreads();

  for (int p = 0; p <= NSTEP; ++p) {
    // zero the reduce buffer
    for (int z = tid; z < 32 * 68; z += 256) ((float*)part)[z] = 0.f;
    __syncthreads();

    const bool active = (layer == 0) ? (p < NSTEP) : (p >= 1);
    const int t = (layer == 0) ? p : (p - 1);
    floatx4 zero = {0.f, 0.f, 0.f, 0.f};
    floatx4 acc_h[2][4], acc_l[2][4];
    for (int a = 0; a < 2; ++a)
      for (int b = 0; b < 4; ++b) { acc_h[a][b] = zero; acc_l[a][b] = zero; }

    if (active) {
      const bool skipH = (wv >= 2) && (t == 0);  // h_{t-1}=0 at t==0
      if (!skipH) {
        if (layer == 0 && wv < 2) {
          int tk[4];
          #pragma unroll
          for (int nt = 0; nt < 4; ++nt) tk[nt] = tokens[t * 64 + nt * 16 + (lane & 15)];
          #pragma unroll 2
          for (int kk = 0; kk < 16; ++kk) {
            half8 ah0 = *(const half8*)&wlds[wv][kk * 2 + 0][lane][0];
            half8 ah1 = *(const half8*)&wlds[wv][kk * 2 + 1][lane][0];
            const unsigned* l0 = (const unsigned*)(lob + ((kk * 2 + 0) << 9) + lane * 8);
            const unsigned* l1 = (const unsigned*)(lob + ((kk * 2 + 1) << 9) + lane * 8);
            half8 al0 = dec8(l0[0], l0[1]);
            half8 al1 = dec8(l1[0], l1[1]);
            int kb = wv * 512 + kk * 32 + ((lane >> 4) * 8);
            #pragma unroll
            for (int nt = 0; nt < 4; ++nt) {
              int tok = tk[nt];
              const float* src = emb + (long)tok * 1024 + kb;
              floatx4 x0 = *(const floatx4*)(src);
              floatx4 x1 = *(const floatx4*)(src + 4);
              float msk = (tok == 0) ? 0.f : 1.f;
              half8 bh, bl;
              #pragma unroll
              for (int q = 0; q < 4; ++q) {
                float v0 = x0[q] * msk;
                float v1 = x1[q] * msk;
                half_t h0 = (half_t)v0, h1v = (half_t)v1;
                bh[q] = h0;     bh[q + 4] = h1v;
                bl[q] = (half_t)((v0 - (float)h0) * 2048.f);
                bl[q + 4] = (half_t)((v1 - (float)h1v) * 2048.f);
              }
              acc_h[0][nt] = __builtin_amdgcn_mfma_f32_16x16x32_f16(ah0, bh, acc_h[0][nt], 0, 0, 0);
              acc_h[1][nt] = __builtin_amdgcn_mfma_f32_16x16x32_f16(ah1, bh, acc_h[1][nt], 0, 0, 0);
              acc_l[0][nt] = __builtin_amdgcn_mfma_f32_16x16x32_f16(ah0, bl, acc_l[0][nt], 0, 0, 0);
              acc_l[0][nt] = __builtin_amdgcn_mfma_f32_16x16x32_f16(al0, bh, acc_l[0][nt], 0, 0, 0);
              acc_l[1][nt] = __builtin_amdgcn_mfma_f32_16x16x32_f16(ah1, bl, acc_l[1][nt], 0, 0, 0);
              acc_l[1][nt] = __builtin_amdgcn_mfma_f32_16x16x32_f16(al1, bh, acc_l[1][nt], 0, 0, 0);
            }
          }
        } else {
          const half_t *abh, *abl;
          int kofs;
          if (wv < 2) {  // layer==1 x-part = h1 at t
            abh = h1hi + ((p - 1) & 1) * 65536;
            abl = h1lo + ((p - 1) & 1) * 65536;
            kofs = wv * 512;
          } else {       // recurrent h-part (own layer)
            abh = (layer == 0 ? h1hi : h2hi) + ((p - 1) & 1) * 65536;
            abl = (layer == 0 ? h1lo : h2lo) + ((p - 1) & 1) * 65536;
            kofs = (wv - 2) * 512;
          }
          #pragma unroll 2
          for (int kk = 0; kk < 16; ++kk) {
            half8 ah0 = *(const half8*)&wlds[wv][kk * 2 + 0][lane][0];
            half8 ah1 = *(const half8*)&wlds[wv][kk * 2 + 1][lane][0];
            const unsigned* l0 = (const unsigned*)(lob + ((kk * 2 + 0) << 9) + lane * 8);
            const unsigned* l1 = (const unsigned*)(lob + ((kk * 2 + 1) << 9) + lane * 8);
            half8 al0 = dec8(l0[0], l0[1]);
            half8 al1 = dec8(l1[0], l1[1]);
            int kb = kofs + kk * 32 + ((lane >> 4) * 8);
            #pragma unroll
            for (int nt = 0; nt < 4; ++nt) {
              int n = nt * 16 + (lane & 15);
              half8 bh = *(const half8*)(abh + n * 1024 + kb);
              half8 bl = *(const half8*)(abl + n * 1024 + kb);
              acc_h[0][nt] = __builtin_amdgcn_mfma_f32_16x16x32_f16(ah0, bh, acc_h[0][nt], 0, 0, 0);
              acc_h[1][nt] = __builtin_amdgcn_mfma_f32_16x16x32_f16(ah1, bh, acc_h[1][nt], 0, 0, 0);
              acc_l[0][nt] = __builtin_amdgcn_mfma_f32_16x16x32_f16(ah0, bl, acc_l[0][nt], 0, 0, 0);
              acc_l[0][nt] = __builtin_amdgcn_mfma_f32_16x16x32_f16(al0, bh, acc_l[0][nt], 0, 0, 0);
              acc_l[1][nt] = __builtin_amdgcn_mfma_f32_16x16x32_f16(ah1, bl, acc_l[1][nt], 0, 0, 0);
              acc_l[1][nt] = __builtin_amdgcn_mfma_f32_16x16x32_f16(al1, bh, acc_l[1][nt], 0, 0, 0);
            }
          }
        }
      }
      // D-frag row = mt*16 + (lane>>4)*4 + q, col = nt*16 + (lane&15); 4 waves atomically reduce
      #pragma unroll
      for (int mt = 0; mt < 2; ++mt)
        #pragma unroll
        for (int nt = 0; nt < 4; ++nt)
          #pragma unroll
          for (int q = 0; q < 4; ++q)
            atomicAdd(&part[mt * 16 + (lane >> 4) * 4 + q][nt * 16 + (lane & 15)],
                      acc_h[mt][nt][q] + INV2048 * acc_l[mt][nt][q]);
    }
    __syncthreads();
    if (active) {
      half_t* hbh = (layer == 0 ? h1hi : h2hi) + (p & 1) * 65536;
      half_t* hbl = (layer == 0 ? h1lo : h2lo) + (p & 1) * 65536;
      #pragma unroll
      for (int pp = 0; pp < 2; ++pp) {
        int pair = tid + pp * 256;
        int u = pair & 7, n = pair >> 3;
        float s0 = part[u][n]      + bsum[0];
        float s1 = part[8 + u][n]  + bsum[1];
        float s2 = part[16 + u][n] + bsum[2];
        float s3 = part[24 + u][n] + bsum[3];
        float is = sigm(s0), fs = sigm(s1), gt = tanh_f(s2), os = sigm(s3);
        float& c = pp ? c1 : c0;
        c = fs * c + is * gt;
        float h = os * tanh_f(c);
        half_t hhi = (half_t)h;
        hbh[n * 1024 + wg * 8 + u] = hhi;
        hbl[n * 1024 + wg * 8 + u] = (half_t)((h - (float)hhi) * 2048.f);
        if (layer == 1)
          __builtin_nontemporal_store(h, &out[((long)t * 64 + n) * 1024 + wg * 8 + u]);
      }
    }
    __builtin_amdgcn_fence(__ATOMIC_RELEASE, "agent");
    gbar(gcnt, root, gdone, p);
    __builtin_amdgcn_fence(__ATOMIC_ACQUIRE, "agent");
  }
}

extern "C" void kernel_launch(void* const* d_in, const int* in_sizes, int n_in,
                              void* d_out, int out_size, void* d_ws, size_t ws_size,
                              hipStream_t stream) {
  const int*   tokens = (const int*)d_in[0];
  const float* emb    = (const float*)d_in[1];
  const float* Wih    = (const float*)d_in[2];
  const float* Whh    = (const float*)d_in[3];
  const float* bih    = (const float*)d_in[4];
  const float* bhh    = (const float*)d_in[5];
  float* out = (float*)d_out;  // reference output dtype is float32

  half_t* whi = (half_t*)d_ws;                                   // 33,554,432 B
  uchar*  wlo = (uchar*)((char*)d_ws + 33554432);                // 16,777,216 B
  char* hb = (char*)d_ws + 50331648;
  half_t* h1hi = (half_t*)(hb);
  half_t* h1lo = (half_t*)(hb + 262144);
  half_t* h2hi = (half_t*)(hb + 524288);
  half_t* h2lo = (half_t*)(hb + 786432);
  int* barblk  = (int*)(hb + 1048576);                           // 16 KB

  hipLaunchKernelGGL(conv_w, dim3(65536), dim3(256), 0, stream, Wih, Whh, whi, wlo);
  hipMemsetAsync(barblk, 0, 16384, stream);

  void* args[] = {(void*)&tokens, (void*)&emb, (void*)&bih, (void*)&bhh,
                  (void*)&whi, (void*)&wlo, (void*)&h1hi, (void*)&h1lo,
                  (void*)&h2hi, (void*)&h2lo, (void*)&barblk, (void*)&out};
  hipError_t e = hipLaunchCooperativeKernel((const void*)lstm_main, dim3(256), dim3(256),
                                            args, 0, stream);
  if (e != hipSuccess) {  // signature ~195: cooperative launch refused (resources)
    hipMemsetAsync(d_out, 0x43, (size_t)out_size * 4, stream);
  }
}

// Round 10
// 23001.424 us; speedup vs baseline: 3.3262x; 1.7275x over previous
//
#include <hip/hip_runtime.h>

typedef _Float16 half_t;
typedef _Float16 half8 __attribute__((ext_vector_type(8)));
typedef float floatx4 __attribute__((ext_vector_type(4)));
typedef int int4v __attribute__((ext_vector_type(4)));
typedef unsigned char uchar;

#define NSTEP 512
#define INV2048 (1.0f / 2048.0f)

// ---- fp8 e4m3fn codec (FTZ below 2^-6; decode is shift-only) ----
__device__ __forceinline__ uchar enc_e4m3(float x) {
  unsigned s = (__builtin_bit_cast(unsigned, x) >> 31) & 1u;
  float a = fabsf(x);
  if (a < 0.015625f) return (uchar)(s << 7);
  int E; float m = frexpf(a, &E);
  int Ee = E - 1;
  int mant = (int)roundf((2.f * m - 1.f) * 8.f);
  if (mant == 8) { Ee++; mant = 0; }
  if (Ee > 8) { Ee = 8; mant = 6; }
  return (uchar)((s << 7) | ((Ee + 7) << 3) | mant);
}

__device__ __forceinline__ half8 dec8(unsigned w0, unsigned w1) {
  half8 r;
  #pragma unroll
  for (int j = 0; j < 8; ++j) {
    unsigned b = ((j < 4 ? w0 : w1) >> (8 * (j & 3))) & 0xffu;
    unsigned p = b & 0x7fu;
    unsigned h = (p ? ((p << 7) + 0x2000u) : 0u) | ((b & 0x80u) << 8);
    unsigned short us = (unsigned short)h;
    r[j] = __builtin_bit_cast(half_t, us);
  }
  return r;
}

__device__ __forceinline__ void unpack8(int4v w0, int4v w1, half8& bh, half8& bl) {
  #pragma unroll
  for (int j = 0; j < 8; ++j) {
    unsigned w = (unsigned)(j < 4 ? w0[j] : w1[j - 4]);
    bh[j] = __builtin_bit_cast(half_t, (unsigned short)(w & 0xffffu));
    bl[j] = __builtin_bit_cast(half_t, (unsigned short)(w >> 16));
  }
}

// hi blob: [layer(2)][wg(128)][wv(8)][frag(16)][lane(64)][i(8)] f16 (32 MB)
// lo blob: same index space, fp8 e4m3 of (v-hi)*2048 (16 MB)
// frag = kk*2+mt; A-row mloc = mt*16+(lane&15) -> gate=mloc>>3, u=mloc&7;
// grow = gate*1024 + wg*8 + u; k = wv*256 + kk*32 + (lane>>4)*8 + i; k<1024 Wih else Whh.
__global__ void conv_w(const float* __restrict__ Wih, const float* __restrict__ Whh,
                       half_t* __restrict__ whi, uchar* __restrict__ wlo) {
  long e = (long)blockIdx.x * 256 + threadIdx.x;  // 2^24
  int i    = (int)(e & 7);
  int lane = (int)((e >> 3) & 63);
  int frag = (int)((e >> 9) & 15);
  int wv   = (int)((e >> 13) & 7);
  int wg   = (int)((e >> 16) & 127);
  int layer = (int)((e >> 23) & 1);
  int mt = frag & 1, kk = frag >> 1;
  int mloc = mt * 16 + (lane & 15);
  int grow = (mloc >> 3) * 1024 + wg * 8 + (mloc & 7);
  int k = wv * 256 + kk * 32 + ((lane >> 4) * 8) + i;
  long base = ((long)layer << 22) + (long)grow * 1024;
  float v = (k < 1024) ? Wih[base + k] : Whh[base + (k - 1024)];
  half_t hi = (half_t)v;
  whi[e] = hi;
  wlo[e] = enc_e4m3((v - (float)hi) * 2048.0f);
}

__device__ __forceinline__ float sigm(float x) { return 1.f / (1.f + __expf(-x)); }
__device__ __forceinline__ float tanh_f(float x) {
  x = fminf(15.f, fmaxf(-15.f, x));
  float e = __expf(-2.f * x);
  return (1.f - e) / (1.f + e);
}

// two-level barrier: 16 groups x 16 WGs, padded counters, monotonic, RELAXED-only
__device__ __forceinline__ void gbar(int* gcnt, int* root, int* gdone, int p) {
  __syncthreads();  // drains vmcnt(0): h sc1-stores complete before flag
  if (threadIdx.x == 0) {
    asm volatile("s_waitcnt vmcnt(0)" ::: "memory");
    int g = (int)blockIdx.x >> 4;
    int a = __hip_atomic_fetch_add(&gcnt[g * 64], 1, __ATOMIC_RELAXED, __HIP_MEMORY_SCOPE_AGENT);
    if (a == 16 * (p + 1) - 1) {
      __hip_atomic_fetch_add(root, 1, __ATOMIC_RELAXED, __HIP_MEMORY_SCOPE_AGENT);
      while (__hip_atomic_load(root, __ATOMIC_RELAXED, __HIP_MEMORY_SCOPE_AGENT) < 16 * (p + 1))
        __builtin_amdgcn_s_sleep(1);
    __hip_atomic_store(&gdone[g * 64], p + 1, __ATOMIC_RELAXED, __HIP_MEMORY_SCOPE_AGENT);
    } else {
      while (__hip_atomic_load(&gdone[g * 64], __ATOMIC_RELAXED, __HIP_MEMORY_SCOPE_AGENT) < p + 1)
        __builtin_amdgcn_s_sleep(1);
    }
  }
  __syncthreads();
}

// 256 WGs x 512 thr (8 waves/CU). WGs [0,128): layer 1 t=p; [128,256): layer 2 t=p-1.
// 8 units/WG (32 gate rows); K=2048 over 8 waves (256 k each; wv<4 x-part, wv>=4 h-part).
// hi f16 LDS-resident (128 KB); fp8 lo from L2; h exchange: rolling 16-slot packed
// uint32 (hi|lo f16), sc1 writes (atomic relaxed agent), PLAIN cached reads (fresh
// addresses each phase -> no staleness; L2 dedups across the XCD's 32 WGs).
// Full L2 invalidate only every 8 phases (slot reuse distance 16 -> provably safe).
__launch_bounds__(512, 1)
__global__ void lstm_main(const int* __restrict__ tokens, const float* __restrict__ emb,
                          const float* __restrict__ bih, const float* __restrict__ bhh,
                          const half_t* __restrict__ whi, const uchar* __restrict__ wlo,
                          unsigned* __restrict__ h1, unsigned* __restrict__ h2,
                          int* __restrict__ barblk, float* __restrict__ out) {
  __shared__ half_t wlds[8][16][64][8];  // 128 KB
  __shared__ float part[32][68];         // 8.7 KB
  const int wgid = blockIdx.x;
  const int layer = wgid >> 7;
  const int wg = wgid & 127;
  const int tid = (int)threadIdx.x;
  const int wv = tid >> 6;
  const int lane = tid & 63;

  int* gcnt  = barblk;
  int* root  = barblk + 1024;
  int* gdone = barblk + 2048;

  // stage hi weights: 128 KB global -> LDS, once
  {
    const int4v* src = (const int4v*)(whi + (((long)(layer * 128 + wg)) << 16));
    int4v* dst = (int4v*)&wlds[0][0][0][0];
    #pragma unroll
    for (int it = 0; it < 16; ++it) dst[it * 512 + tid] = src[it * 512 + tid];
  }
  const uchar* lobw = wlo + (((long)(layer * 128 + wg)) << 16) + wv * 8192;

  float bsum[4];
  {
    int u = tid & 7;
    for (int g = 0; g < 4; ++g) {
      int bi = layer * 4096 + g * 1024 + wg * 8 + u;
      bsum[g] = bih[bi] + bhh[bi];
    }
  }
  float c = 0.f;
  __syncthreads();

  for (int p = 0; p <= NSTEP; ++p) {
    for (int z = tid; z < 32 * 68; z += 512) ((float*)part)[z] = 0.f;
    __syncthreads();

    const bool active = (layer == 0) ? (p < NSTEP) : (p >= 1);
    const int t = (layer == 0) ? p : (p - 1);
    floatx4 zero = {0.f, 0.f, 0.f, 0.f};
    floatx4 acc_h[2][4], acc_l[2][4];
    for (int a = 0; a < 2; ++a)
      for (int b = 0; b < 4; ++b) { acc_h[a][b] = zero; acc_l[a][b] = zero; }

    if (active) {
      const bool skipH = (wv >= 4) && (t == 0);
      if (!skipH) {
        if (layer == 0 && wv < 4) {
          // x-part from f32 embedding (token 0 -> zero row), split hi/lo on the fly
          int tk[4];
          #pragma unroll
          for (int nt = 0; nt < 4; ++nt) tk[nt] = tokens[t * 64 + nt * 16 + (lane & 15)];
          #pragma unroll 2
          for (int kk = 0; kk < 8; ++kk) {
            half8 ah0 = *(const half8*)&wlds[wv][kk * 2 + 0][lane][0];
            half8 ah1 = *(const half8*)&wlds[wv][kk * 2 + 1][lane][0];
            const unsigned* l0 = (const unsigned*)(lobw + ((kk * 2 + 0) << 9) + lane * 8);
            const unsigned* l1 = (const unsigned*)(lobw + ((kk * 2 + 1) << 9) + lane * 8);
            half8 al0 = dec8(l0[0], l0[1]);
            half8 al1 = dec8(l1[0], l1[1]);
            int kb = wv * 256 + kk * 32 + ((lane >> 4) * 8);
            #pragma unroll
            for (int nt = 0; nt < 4; ++nt) {
              int tok = tk[nt];
              const float* src = emb + (long)tok * 1024 + kb;
              floatx4 x0 = *(const floatx4*)(src);
              floatx4 x1 = *(const floatx4*)(src + 4);
              float msk = (tok == 0) ? 0.f : 1.f;
              half8 bh, bl;
              #pragma unroll
              for (int q = 0; q < 4; ++q) {
                float v0 = x0[q] * msk;
                float v1 = x1[q] * msk;
                half_t h0 = (half_t)v0, h1v = (half_t)v1;
                bh[q] = h0;     bh[q + 4] = h1v;
                bl[q] = (half_t)((v0 - (float)h0) * 2048.f);
                bl[q + 4] = (half_t)((v1 - (float)h1v) * 2048.f);
              }
              acc_h[0][nt] = __builtin_amdgcn_mfma_f32_16x16x32_f16(ah0, bh, acc_h[0][nt], 0, 0, 0);
              acc_h[1][nt] = __builtin_amdgcn_mfma_f32_16x16x32_f16(ah1, bh, acc_h[1][nt], 0, 0, 0);
              acc_l[0][nt] = __builtin_amdgcn_mfma_f32_16x16x32_f16(ah0, bl, acc_l[0][nt], 0, 0, 0);
              acc_l[0][nt] = __builtin_amdgcn_mfma_f32_16x16x32_f16(al0, bh, acc_l[0][nt], 0, 0, 0);
              acc_l[1][nt] = __builtin_amdgcn_mfma_f32_16x16x32_f16(ah1, bl, acc_l[1][nt], 0, 0, 0);
              acc_l[1][nt] = __builtin_amdgcn_mfma_f32_16x16x32_f16(al1, bh, acc_l[1][nt], 0, 0, 0);
            }
          }
        } else {
          const unsigned* ab;
          int kofs;
          if (wv < 4) {  // layer==1 x-part = h1 at t
            ab = h1 + ((p - 1) & 15) * 65536;
            kofs = wv * 256;
          } else {       // recurrent h-part (own layer)
            ab = (layer == 0 ? h1 : h2) + ((p - 1) & 15) * 65536;
            kofs = (wv - 4) * 256;
          }
          #pragma unroll 2
          for (int kk = 0; kk < 8; ++kk) {
            half8 ah0 = *(const half8*)&wlds[wv][kk * 2 + 0][lane][0];
            half8 ah1 = *(const half8*)&wlds[wv][kk * 2 + 1][lane][0];
            const unsigned* l0 = (const unsigned*)(lobw + ((kk * 2 + 0) << 9) + lane * 8);
            const unsigned* l1 = (const unsigned*)(lobw + ((kk * 2 + 1) << 9) + lane * 8);
            half8 al0 = dec8(l0[0], l0[1]);
            half8 al1 = dec8(l1[0], l1[1]);
            int kb = kofs + kk * 32 + ((lane >> 4) * 8);
            #pragma unroll
            for (int nt = 0; nt < 4; ++nt) {
              int n = nt * 16 + (lane & 15);
              const int4v* s = (const int4v*)(ab + n * 1024 + kb);
              int4v w0 = s[0], w1 = s[1];
              half8 bh, bl;
              unpack8(w0, w1, bh, bl);
              acc_h[0][nt] = __builtin_amdgcn_mfma_f32_16x16x32_f16(ah0, bh, acc_h[0][nt], 0, 0, 0);
              acc_h[1][nt] = __builtin_amdgcn_mfma_f32_16x16x32_f16(ah1, bh, acc_h[1][nt], 0, 0, 0);
              acc_l[0][nt] = __builtin_amdgcn_mfma_f32_16x16x32_f16(ah0, bl, acc_l[0][nt], 0, 0, 0);
              acc_l[0][nt] = __builtin_amdgcn_mfma_f32_16x16x32_f16(al0, bh, acc_l[0][nt], 0, 0, 0);
              acc_l[1][nt] = __builtin_amdgcn_mfma_f32_16x16x32_f16(ah1, bl, acc_l[1][nt], 0, 0, 0);
              acc_l[1][nt] = __builtin_amdgcn_mfma_f32_16x16x32_f16(al1, bh, acc_l[1][nt], 0, 0, 0);
            }
          }
        }
      }
      #pragma unroll
      for (int mt = 0; mt < 2; ++mt)
        #pragma unroll
        for (int nt = 0; nt < 4; ++nt)
          #pragma unroll
          for (int q = 0; q < 4; ++q)
            atomicAdd(&part[mt * 16 + (lane >> 4) * 4 + q][nt * 16 + (lane & 15)],
                      acc_h[mt][nt][q] + INV2048 * acc_l[mt][nt][q]);
    }
    __syncthreads();
    if (active) {
      int u = tid & 7, n = tid >> 3;  // 512 threads = 8 units x 64 batch
      float s0 = part[u][n]      + bsum[0];
      float s1 = part[8 + u][n]  + bsum[1];
      float s2 = part[16 + u][n] + bsum[2];
      float s3 = part[24 + u][n] + bsum[3];
      float is = sigm(s0), fs = sigm(s1), gt = tanh_f(s2), os = sigm(s3);
      c = fs * c + is * gt;
      float h = os * tanh_f(c);
      half_t hhi = (half_t)h;
      half_t hlo = (half_t)((h - (float)hhi) * 2048.f);
      unsigned pk = (unsigned)__builtin_bit_cast(unsigned short, hhi) |
                    ((unsigned)__builtin_bit_cast(unsigned short, hlo) << 16);
      unsigned* hb = (layer == 0 ? h1 : h2) + (p & 15) * 65536;
      __hip_atomic_store(&hb[n * 1024 + wg * 8 + u], pk,
                         __ATOMIC_RELAXED, __HIP_MEMORY_SCOPE_AGENT);
      if (layer == 1)
        __builtin_nontemporal_store(h, &out[((long)t * 64 + n) * 1024 + wg * 8 + u]);
    }
    gbar(gcnt, root, gdone, p);
    if ((p & 7) == 7)  // periodic L2 invalidate: bounds staleness of rolling slots
      __builtin_amdgcn_fence(__ATOMIC_ACQUIRE, "agent");
  }
}

extern "C" void kernel_launch(void* const* d_in, const int* in_sizes, int n_in,
                              void* d_out, int out_size, void* d_ws, size_t ws_size,
                              hipStream_t stream) {
  const int*   tokens = (const int*)d_in[0];
  const float* emb    = (const float*)d_in[1];
  const float* Wih    = (const float*)d_in[2];
  const float* Whh    = (const float*)d_in[3];
  const float* bih    = (const float*)d_in[4];
  const float* bhh    = (const float*)d_in[5];
  float* out = (float*)d_out;

  half_t*   whi = (half_t*)d_ws;                          // 32 MB
  uchar*    wlo = (uchar*)((char*)d_ws + 33554432);       // 16 MB
  unsigned* h1  = (unsigned*)((char*)d_ws + 50331648);    // 4 MB (16 slots)
  unsigned* h2  = (unsigned*)((char*)d_ws + 54525952);    // 4 MB
  int*   barblk = (int*)((char*)d_ws + 58720256);         // 16 KB

  hipLaunchKernelGGL(conv_w, dim3(65536), dim3(256), 0, stream, Wih, Whh, whi, wlo);
  hipMemsetAsync(barblk, 0, 16384, stream);

  void* args[] = {(void*)&tokens, (void*)&emb, (void*)&bih, (void*)&bhh,
                  (void*)&whi, (void*)&wlo, (void*)&h1, (void*)&h2,
                  (void*)&barblk, (void*)&out};
  hipError_t e = hipLaunchCooperativeKernel((const void*)lstm_main, dim3(256), dim3(512),
                                            args, 0, stream);
  if (e != hipSuccess) {
    hipMemsetAsync(d_out, 0x43, (size_t)out_size * 4, stream);
  }
}

// Round 11
// 22020.264 us; speedup vs baseline: 3.4744x; 1.0446x over previous
//
#include <hip/hip_runtime.h>

typedef _Float16 half_t;
typedef _Float16 half8 __attribute__((ext_vector_type(8)));
typedef float floatx4 __attribute__((ext_vector_type(4)));
typedef int int4v __attribute__((ext_vector_type(4)));
typedef unsigned uint4v __attribute__((ext_vector_type(4)));
typedef unsigned char uchar;

#define NSTEP 512
#define INV2048 (1.0f / 2048.0f)
#define NSLOT 32
#define SLOTE 65536  // 64 batch x 1024 units, elements per ring slot

// ---- e5m2 codec: encode = f16 top byte (w/ rounding); decode = byte<<8 ----
__device__ __forceinline__ uchar enc_e5m2(float x) {
  half_t h = (half_t)x;
  unsigned b = (unsigned)__builtin_bit_cast(unsigned short, h);
  return (uchar)(((b + 0x80u) >> 8) & 0xffu);  // RN-ish; |x|<=0.5 -> no sign overflow
}

__device__ __forceinline__ half8 dec8(unsigned w0, unsigned w1) {
  uint4v u;
  u[0] = ((w0 & 0x000000ffu) << 8) | ((w0 & 0x0000ff00u) << 16);
  u[1] = ((w0 & 0x00ff0000u) >> 8) | (w0 & 0xff000000u);
  u[2] = ((w1 & 0x000000ffu) << 8) | ((w1 & 0x0000ff00u) << 16);
  u[3] = ((w1 & 0x00ff0000u) >> 8) | (w1 & 0xff000000u);
  return __builtin_bit_cast(half8, u);
}

// hi blob: [layer(2)][wg(128)][wv(8)][frag(16)][lane(64)][i(8)] f16 (32 MB)
// lo blob: same index space, e5m2 of (v-hi)*2048 (16 MB)
// frag = kk*2+mt; A-row mloc = mt*16+(lane&15) -> gate=mloc>>3, u=mloc&7;
// grow = gate*1024 + wg*8 + u; k = wv*256 + kk*32 + (lane>>4)*8 + i; k<1024 Wih else Whh.
__global__ void conv_w(const float* __restrict__ Wih, const float* __restrict__ Whh,
                       half_t* __restrict__ whi, uchar* __restrict__ wlo) {
  long e = (long)blockIdx.x * 256 + threadIdx.x;  // 2^24
  int i    = (int)(e & 7);
  int lane = (int)((e >> 3) & 63);
  int frag = (int)((e >> 9) & 15);
  int wv   = (int)((e >> 13) & 7);
  int wg   = (int)((e >> 16) & 127);
  int layer = (int)((e >> 23) & 1);
  int mt = frag & 1, kk = frag >> 1;
  int mloc = mt * 16 + (lane & 15);
  int grow = (mloc >> 3) * 1024 + wg * 8 + (mloc & 7);
  int k = wv * 256 + kk * 32 + ((lane >> 4) * 8) + i;
  long base = ((long)layer << 22) + (long)grow * 1024;
  float v = (k < 1024) ? Wih[base + k] : Whh[base + (k - 1024)];
  half_t hi = (half_t)v;
  whi[e] = hi;
  wlo[e] = enc_e5m2((v - (float)hi) * 2048.0f);
}

__device__ __forceinline__ float sigm(float x) { return 1.f / (1.f + __expf(-x)); }
__device__ __forceinline__ float tanh_f(float x) {
  x = fminf(15.f, fmaxf(-15.f, x));
  float e = __expf(-2.f * x);
  return (1.f - e) / (1.f + e);
}

// two-level barrier: 16 groups x 16 WGs, padded counters, monotonic, RELAXED-only
__device__ __forceinline__ void gbar(int* gcnt, int* root, int* gdone, int p) {
  __syncthreads();  // all waves drain vmcnt(0) at this barrier
  if (threadIdx.x == 0) {
    asm volatile("s_waitcnt vmcnt(0)" ::: "memory");
    int g = (int)blockIdx.x >> 4;
    int a = __hip_atomic_fetch_add(&gcnt[g * 64], 1, __ATOMIC_RELAXED, __HIP_MEMORY_SCOPE_AGENT);
    if (a == 16 * (p + 1) - 1) {
      __hip_atomic_fetch_add(root, 1, __ATOMIC_RELAXED, __HIP_MEMORY_SCOPE_AGENT);
      while (__hip_atomic_load(root, __ATOMIC_RELAXED, __HIP_MEMORY_SCOPE_AGENT) < 16 * (p + 1))
        __builtin_amdgcn_s_sleep(1);
      __hip_atomic_store(&gdone[g * 64], p + 1, __ATOMIC_RELAXED, __HIP_MEMORY_SCOPE_AGENT);
    } else {
      while (__hip_atomic_load(&gdone[g * 64], __ATOMIC_RELAXED, __HIP_MEMORY_SCOPE_AGENT) < p + 1)
        __builtin_amdgcn_s_sleep(1);
    }
  }
  __syncthreads();
}

// 256 WGs x 512 thr (8 waves/CU). WGs [0,128): layer 1 t=p; [128,256): layer 2 t=p-1.
// hi f16 LDS-resident; e5m2 lo from L2; h exchange: 32-slot rolling rings, split hi/lo
// f16, relaxed-agent stores, plain cached reads (fresh addresses), L2 invalidate only
// every 16 phases (reuse distance 32 -> provably safe). Act loads double-buffered.
__launch_bounds__(512, 1)
__global__ void lstm_main(const int* __restrict__ tokens, const float* __restrict__ emb,
                          const float* __restrict__ bih, const float* __restrict__ bhh,
                          const half_t* __restrict__ whi, const uchar* __restrict__ wlo,
                          half_t* __restrict__ h1h, half_t* __restrict__ h1l,
                          half_t* __restrict__ h2h, half_t* __restrict__ h2l,
                          int* __restrict__ barblk, float* __restrict__ out) {
  __shared__ half_t wlds[8][16][64][8];  // 128 KB
  __shared__ float part[2][32][68];      // 17.4 KB
  const int wgid = blockIdx.x;
  const int layer = wgid >> 7;
  const int wg = wgid & 127;
  const int tid = (int)threadIdx.x;
  const int wv = tid >> 6;
  const int lane = tid & 63;
  const int ln15 = lane & 15;
  const int kr = (lane >> 4) * 8;

  int* gcnt  = barblk;
  int* root  = barblk + 1024;
  int* gdone = barblk + 2048;

  {  // stage hi weights: 128 KB global -> LDS, once
    const int4v* src = (const int4v*)(whi + (((long)(layer * 128 + wg)) << 16));
    int4v* dst = (int4v*)&wlds[0][0][0][0];
    #pragma unroll
    for (int it = 0; it < 16; ++it) dst[it * 512 + tid] = src[it * 512 + tid];
  }
  const uchar* lobw = wlo + (((long)(layer * 128 + wg)) << 16) + wv * 8192;

  float bsum[4];
  {
    int u = tid & 7;
    for (int g = 0; g < 4; ++g) {
      int bi = layer * 4096 + g * 1024 + wg * 8 + u;
      bsum[g] = bih[bi] + bhh[bi];
    }
  }
  float c = 0.f;
  __syncthreads();

  for (int p = 0; p <= NSTEP; ++p) {
    for (int z = tid; z < 2 * 32 * 68; z += 512) ((float*)part)[z] = 0.f;
    __syncthreads();

    const bool active = (layer == 0) ? (p < NSTEP) : (p >= 1);
    const int t = (layer == 0) ? p : (p - 1);
    floatx4 zero = {0.f, 0.f, 0.f, 0.f};
    floatx4 acc_h[2][4], acc_l[2][4];
    for (int a = 0; a < 2; ++a)
      for (int b = 0; b < 4; ++b) { acc_h[a][b] = zero; acc_l[a][b] = zero; }

    if (active) {
      const bool skipH = (wv >= 4) && (t == 0);
      if (!skipH) {
        // preload e5m2 lo-weight words for all 8 kk (L2-resident)
        unsigned lw[8][4];
        #pragma unroll
        for (int kk = 0; kk < 8; ++kk) {
          const unsigned* l0 = (const unsigned*)(lobw + ((kk * 2 + 0) << 9) + lane * 8);
          const unsigned* l1 = (const unsigned*)(lobw + ((kk * 2 + 1) << 9) + lane * 8);
          lw[kk][0] = l0[0]; lw[kk][1] = l0[1];
          lw[kk][2] = l1[0]; lw[kk][3] = l1[1];
        }

        if (layer == 0 && wv < 4) {
          // x-part from f32 embedding, split hi/lo on the fly; double-buffered loads
          int tk[4]; const float* rowp[4]; float msk[4];
          #pragma unroll
          for (int nt = 0; nt < 4; ++nt) {
            tk[nt] = tokens[t * 64 + nt * 16 + ln15];
            rowp[nt] = emb + (long)tk[nt] * 1024;
            msk[nt] = (tk[nt] == 0) ? 0.f : 1.f;
          }
          floatx4 bx0[2][4], bx1[2][4];
          {
            int kb = wv * 256 + kr;
            #pragma unroll
            for (int nt = 0; nt < 4; ++nt) {
              bx0[0][nt] = *(const floatx4*)(rowp[nt] + kb);
              bx1[0][nt] = *(const floatx4*)(rowp[nt] + kb + 4);
            }
          }
          #pragma unroll
          for (int kk = 0; kk < 8; ++kk) {
            const int cb = kk & 1, nx = cb ^ 1;
            if (kk < 7) {
              int kb = wv * 256 + (kk + 1) * 32 + kr;
              #pragma unroll
              for (int nt = 0; nt < 4; ++nt) {
                bx0[nx][nt] = *(const floatx4*)(rowp[nt] + kb);
                bx1[nx][nt] = *(const floatx4*)(rowp[nt] + kb + 4);
              }
            }
            half8 ah0 = *(const half8*)&wlds[wv][kk * 2 + 0][lane][0];
            half8 ah1 = *(const half8*)&wlds[wv][kk * 2 + 1][lane][0];
            half8 al0 = dec8(lw[kk][0], lw[kk][1]);
            half8 al1 = dec8(lw[kk][2], lw[kk][3]);
            #pragma unroll
            for (int nt = 0; nt < 4; ++nt) {
              half8 bh, bl;
              #pragma unroll
              for (int q = 0; q < 4; ++q) {
                float v0 = bx0[cb][nt][q] * msk[nt];
                float v1 = bx1[cb][nt][q] * msk[nt];
                half_t h0 = (half_t)v0, h1v = (half_t)v1;
                bh[q] = h0;     bh[q + 4] = h1v;
                bl[q] = (half_t)((v0 - (float)h0) * 2048.f);
                bl[q + 4] = (half_t)((v1 - (float)h1v) * 2048.f);
              }
              acc_h[0][nt] = __builtin_amdgcn_mfma_f32_16x16x32_f16(ah0, bh, acc_h[0][nt], 0, 0, 0);
              acc_h[1][nt] = __builtin_amdgcn_mfma_f32_16x16x32_f16(ah1, bh, acc_h[1][nt], 0, 0, 0);
              acc_l[0][nt] = __builtin_amdgcn_mfma_f32_16x16x32_f16(ah0, bl, acc_l[0][nt], 0, 0, 0);
              acc_l[0][nt] = __builtin_amdgcn_mfma_f32_16x16x32_f16(al0, bh, acc_l[0][nt], 0, 0, 0);
              acc_l[1][nt] = __builtin_amdgcn_mfma_f32_16x16x32_f16(ah1, bl, acc_l[1][nt], 0, 0, 0);
              acc_l[1][nt] = __builtin_amdgcn_mfma_f32_16x16x32_f16(al1, bh, acc_l[1][nt], 0, 0, 0);
            }
          }
        } else {
          const half_t *abh, *abl;
          int kofs;
          const int slot = (p - 1) & (NSLOT - 1);
          if (wv < 4) {  // layer==1 x-part = h1 at t
            abh = h1h + slot * SLOTE; abl = h1l + slot * SLOTE;
            kofs = wv * 256;
          } else {       // recurrent h-part (own layer)
            abh = (layer == 0 ? h1h : h2h) + slot * SLOTE;
            abl = (layer == 0 ? h1l : h2l) + slot * SLOTE;
            kofs = (wv - 4) * 256;
          }
          half8 bufh[2][4], bufl[2][4];
          {
            int kb = kofs + kr;
            #pragma unroll
            for (int nt = 0; nt < 4; ++nt) {
              bufh[0][nt] = *(const half8*)(abh + (nt * 16 + ln15) * 1024 + kb);
              bufl[0][nt] = *(const half8*)(abl + (nt * 16 + ln15) * 1024 + kb);
            }
          }
          #pragma unroll
          for (int kk = 0; kk < 8; ++kk) {
            const int cb = kk & 1, nx = cb ^ 1;
            if (kk < 7) {
              int kb = kofs + (kk + 1) * 32 + kr;
              #pragma unroll
              for (int nt = 0; nt < 4; ++nt) {
                bufh[nx][nt] = *(const half8*)(abh + (nt * 16 + ln15) * 1024 + kb);
                bufl[nx][nt] = *(const half8*)(abl + (nt * 16 + ln15) * 1024 + kb);
              }
            }
            half8 ah0 = *(const half8*)&wlds[wv][kk * 2 + 0][lane][0];
            half8 ah1 = *(const half8*)&wlds[wv][kk * 2 + 1][lane][0];
            half8 al0 = dec8(lw[kk][0], lw[kk][1]);
            half8 al1 = dec8(lw[kk][2], lw[kk][3]);
            #pragma unroll
            for (int nt = 0; nt < 4; ++nt) {
              half8 bh = bufh[cb][nt], bl = bufl[cb][nt];
              acc_h[0][nt] = __builtin_amdgcn_mfma_f32_16x16x32_f16(ah0, bh, acc_h[0][nt], 0, 0, 0);
              acc_h[1][nt] = __builtin_amdgcn_mfma_f32_16x16x32_f16(ah1, bh, acc_h[1][nt], 0, 0, 0);
              acc_l[0][nt] = __builtin_amdgcn_mfma_f32_16x16x32_f16(ah0, bl, acc_l[0][nt], 0, 0, 0);
              acc_l[0][nt] = __builtin_amdgcn_mfma_f32_16x16x32_f16(al0, bh, acc_l[0][nt], 0, 0, 0);
              acc_l[1][nt] = __builtin_amdgcn_mfma_f32_16x16x32_f16(ah1, bl, acc_l[1][nt], 0, 0, 0);
              acc_l[1][nt] = __builtin_amdgcn_mfma_f32_16x16x32_f16(al1, bh, acc_l[1][nt], 0, 0, 0);
            }
          }
        }
      }
      // staggered 2-array reduce: waves 0-3 -> part[0], waves 4-7 -> part[1]
      #pragma unroll
      for (int mt = 0; mt < 2; ++mt)
        #pragma unroll
        for (int idx = 0; idx < 4; ++idx) {
          int nt = (idx + wv) & 3;
          #pragma unroll
          for (int q = 0; q < 4; ++q)
            atomicAdd(&part[wv >> 2][mt * 16 + (lane >> 4) * 4 + q][nt * 16 + ln15],
                      acc_h[mt][nt][q] + INV2048 * acc_l[mt][nt][q]);
        }
    }
    __syncthreads();
    if (active) {
      int u = tid & 7, n = tid >> 3;
      float s0 = part[0][u][n]      + part[1][u][n]      + bsum[0];
      float s1 = part[0][8 + u][n]  + part[1][8 + u][n]  + bsum[1];
      float s2 = part[0][16 + u][n] + part[1][16 + u][n] + bsum[2];
      float s3 = part[0][24 + u][n] + part[1][24 + u][n] + bsum[3];
      float is = sigm(s0), fs = sigm(s1), gt = tanh_f(s2), os = sigm(s3);
      c = fs * c + is * gt;
      float h = os * tanh_f(c);
      half_t hhi = (half_t)h;
      half_t hlo = (half_t)((h - (float)hhi) * 2048.f);
      const int wslot = p & (NSLOT - 1);
      half_t* hbh = (layer == 0 ? h1h : h2h) + wslot * SLOTE;
      half_t* hbl = (layer == 0 ? h1l : h2l) + wslot * SLOTE;
      __hip_atomic_store((unsigned short*)&hbh[n * 1024 + wg * 8 + u],
                         __builtin_bit_cast(unsigned short, hhi),
                         __ATOMIC_RELAXED, __HIP_MEMORY_SCOPE_AGENT);
      __hip_atomic_store((unsigned short*)&hbl[n * 1024 + wg * 8 + u],
                         __builtin_bit_cast(unsigned short, hlo),
                         __ATOMIC_RELAXED, __HIP_MEMORY_SCOPE_AGENT);
      if (layer == 1)
        __builtin_nontemporal_store(h, &out[((long)t * 64 + n) * 1024 + wg * 8 + u]);
    }
    gbar(gcnt, root, gdone, p);
    if ((p & 15) == 15)  // periodic L2/L1 invalidate: bounds ring staleness (16 < 32)
      __builtin_amdgcn_fence(__ATOMIC_ACQUIRE, "agent");
  }
}

extern "C" void kernel_launch(void* const* d_in, const int* in_sizes, int n_in,
                              void* d_out, int out_size, void* d_ws, size_t ws_size,
                              hipStream_t stream) {
  const int*   tokens = (const int*)d_in[0];
  const float* emb    = (const float*)d_in[1];
  const float* Wih    = (const float*)d_in[2];
  const float* Whh    = (const float*)d_in[3];
  const float* bih    = (const float*)d_in[4];
  const float* bhh    = (const float*)d_in[5];
  float* out = (float*)d_out;

  half_t* whi = (half_t*)d_ws;                            // 32 MB
  uchar*  wlo = (uchar*)((char*)d_ws + 33554432);         // 16 MB
  half_t* h1h = (half_t*)((char*)d_ws + 50331648);        // 4 MB (32 slots)
  half_t* h1l = (half_t*)((char*)d_ws + 54525952);        // 4 MB
  half_t* h2h = (half_t*)((char*)d_ws + 58720256);        // 4 MB
  half_t* h2l = (half_t*)((char*)d_ws + 62914560);        // 4 MB
  int* barblk = (int*)((char*)d_ws + 67108864);           // 16 KB

  hipLaunchKernelGGL(conv_w, dim3(65536), dim3(256), 0, stream, Wih, Whh, whi, wlo);
  hipMemsetAsync(barblk, 0, 16384, stream);

  void* args[] = {(void*)&tokens, (void*)&emb, (void*)&bih, (void*)&bhh,
                  (void*)&whi, (void*)&wlo, (void*)&h1h, (void*)&h1l,
                  (void*)&h2h, (void*)&h2l, (void*)&barblk, (void*)&out};
  hipError_t e = hipLaunchCooperativeKernel((const void*)lstm_main, dim3(256), dim3(512),
                                            args, 0, stream);
  if (e != hipSuccess) {
    hipMemsetAsync(d_out, 0x43, (size_t)out_size * 4, stream);
  }
}

// Round 12
// 21264.569 us; speedup vs baseline: 3.5979x; 1.0355x over previous
//
#include <hip/hip_runtime.h>

typedef _Float16 half_t;
typedef _Float16 half8 __attribute__((ext_vector_type(8)));
typedef float floatx4 __attribute__((ext_vector_type(4)));
typedef int int4v __attribute__((ext_vector_type(4)));
typedef unsigned uint4v __attribute__((ext_vector_type(4)));
typedef unsigned char uchar;

#define NSTEP 512
#define INV2048 (1.0f / 2048.0f)
#define NSLOT 32
#define SLOTE 65536  // 64 batch x 1024 units per ring slot

// ---- e5m2 codec: encode = f16 top byte (w/ rounding); decode = byte<<8 ----
__device__ __forceinline__ uchar enc_e5m2(float x) {
  half_t h = (half_t)x;
  unsigned b = (unsigned)__builtin_bit_cast(unsigned short, h);
  return (uchar)(((b + 0x80u) >> 8) & 0xffu);
}

__device__ __forceinline__ half8 dec8(unsigned w0, unsigned w1) {
  uint4v u;
  u[0] = ((w0 & 0x000000ffu) << 8) | ((w0 & 0x0000ff00u) << 16);
  u[1] = ((w0 & 0x00ff0000u) >> 8) | (w0 & 0xff000000u);
  u[2] = ((w1 & 0x000000ffu) << 8) | ((w1 & 0x0000ff00u) << 16);
  u[3] = ((w1 & 0x00ff0000u) >> 8) | (w1 & 0xff000000u);
  return __builtin_bit_cast(half8, u);
}

// hi blob: [layer(2)][wg(128)][wv(8)][frag(16)][lane(64)][i(8)] f16 (32 MB)
// lo blob: same index space, e5m2 of (v-hi)*2048 (16 MB)
__global__ void conv_w(const float* __restrict__ Wih, const float* __restrict__ Whh,
                       half_t* __restrict__ whi, uchar* __restrict__ wlo) {
  long e = (long)blockIdx.x * 256 + threadIdx.x;  // 2^24
  int i    = (int)(e & 7);
  int lane = (int)((e >> 3) & 63);
  int frag = (int)((e >> 9) & 15);
  int wv   = (int)((e >> 13) & 7);
  int wg   = (int)((e >> 16) & 127);
  int layer = (int)((e >> 23) & 1);
  int mt = frag & 1, kk = frag >> 1;
  int mloc = mt * 16 + (lane & 15);
  int grow = (mloc >> 3) * 1024 + wg * 8 + (mloc & 7);
  int k = wv * 256 + kk * 32 + ((lane >> 4) * 8) + i;
  long base = ((long)layer << 22) + (long)grow * 1024;
  float v = (k < 1024) ? Wih[base + k] : Whh[base + (k - 1024)];
  half_t hi = (half_t)v;
  whi[e] = hi;
  wlo[e] = enc_e5m2((v - (float)hi) * 2048.0f);
}

__device__ __forceinline__ float sigm(float x) { return 1.f / (1.f + __expf(-x)); }
__device__ __forceinline__ float tanh_f(float x) {
  x = fminf(15.f, fmaxf(-15.f, x));
  float e = __expf(-2.f * x);
  return (1.f - e) / (1.f + e);
}

__device__ __forceinline__ int ldflag(const int* p) {
  return __hip_atomic_load(p, __ATOMIC_RELAXED, __HIP_MEMORY_SCOPE_AGENT);
}

// 256 WGs x 512 thr. WGs [0,128): layer 0; [128,256): layer 1. Layers DECOUPLED:
// per-layer per-step 2-level completion counters -> monotonic done1/done2.
// L0 step t waits: done1>=t (own prev) && done2>=t-15 (ring reuse, lag<=16).
// L1 step t waits: done1>=t+1 (h1[t]) && done2>=t (own prev).
// h rings 32 slots; relaxed-agent sc1 stores; plain cached reads; acquire-fence
// every 8 own-steps (spread<=17, advance>=15 between ring laps -> provably fresh).
__launch_bounds__(512, 1)
__global__ void lstm_main(const int* __restrict__ tokens, const float* __restrict__ emb,
                          const float* __restrict__ bih, const float* __restrict__ bhh,
                          const half_t* __restrict__ whi, const uchar* __restrict__ wlo,
                          half_t* __restrict__ h1h, half_t* __restrict__ h1l,
                          half_t* __restrict__ h2h, half_t* __restrict__ h2l,
                          int* __restrict__ flagblk, float* __restrict__ out) {
  __shared__ half_t wlds[8][16][64][8];  // 128 KB
  __shared__ float part[2][32][68];      // 17.4 KB
  const int wgid = blockIdx.x;
  const int layer = wgid >> 7;
  const int wg = wgid & 127;
  const int tid = (int)threadIdx.x;
  const int wv = tid >> 6;
  const int lane = tid & 63;
  const int ln15 = lane & 15;
  const int kr = (lane >> 4) * 8;

  int* sub1  = flagblk;             // [512][8] stride 16
  int* sub2  = flagblk + 65536;
  int* mst1  = flagblk + 131072;    // [512] stride 16
  int* mst2  = flagblk + 139264;
  int* done1 = flagblk + 147456;
  int* done2 = flagblk + 147472;

  {  // stage hi weights: 128 KB global -> LDS, once
    const int4v* src = (const int4v*)(whi + (((long)(layer * 128 + wg)) << 16));
    int4v* dst = (int4v*)&wlds[0][0][0][0];
    #pragma unroll
    for (int it = 0; it < 16; ++it) dst[it * 512 + tid] = src[it * 512 + tid];
  }
  const uchar* lobw = wlo + (((long)(layer * 128 + wg)) << 16) + wv * 8192;

  float bsum[4];
  {
    int u = tid & 7;
    for (int g = 0; g < 4; ++g) {
      int bi = layer * 4096 + g * 1024 + wg * 8 + u;
      bsum[g] = bih[bi] + bhh[bi];
    }
  }
  float c = 0.f;
  __syncthreads();

  for (int t = 0; t < NSTEP; ++t) {
    if (tid == 0) {
      const int n1 = (layer == 0) ? t : t + 1;
      const int n2 = (layer == 0) ? t - 15 : t;
      while (ldflag(done1) < n1) __builtin_amdgcn_s_sleep(4);
      while (ldflag(done2) < n2) __builtin_amdgcn_s_sleep(4);
    }
    __syncthreads();
    for (int z = tid; z < 2 * 32 * 68; z += 512) ((float*)part)[z] = 0.f;
    __syncthreads();

    floatx4 zero = {0.f, 0.f, 0.f, 0.f};
    floatx4 acc_h[2][4], acc_l[2][4];
    for (int a = 0; a < 2; ++a)
      for (int b = 0; b < 4; ++b) { acc_h[a][b] = zero; acc_l[a][b] = zero; }

    const bool skipH = (wv >= 4) && (t == 0);
    if (!skipH) {
      // preload e5m2 lo-weight words for all 8 kk (L2-resident)
      unsigned lw[8][4];
      #pragma unroll
      for (int kk = 0; kk < 8; ++kk) {
        const unsigned* l0 = (const unsigned*)(lobw + ((kk * 2 + 0) << 9) + lane * 8);
        const unsigned* l1 = (const unsigned*)(lobw + ((kk * 2 + 1) << 9) + lane * 8);
        lw[kk][0] = l0[0]; lw[kk][1] = l0[1];
        lw[kk][2] = l1[0]; lw[kk][3] = l1[1];
      }

      if (layer == 0 && wv < 4) {
        // x-part from f32 embedding (token 0 -> zero row), split on the fly
        int tk[4]; const float* rowp[4]; float msk[4];
        #pragma unroll
        for (int nt = 0; nt < 4; ++nt) {
          tk[nt] = tokens[t * 64 + nt * 16 + ln15];
          rowp[nt] = emb + (long)tk[nt] * 1024;
          msk[nt] = (tk[nt] == 0) ? 0.f : 1.f;
        }
        floatx4 bx0[2][4], bx1[2][4];
        {
          int kb = wv * 256 + kr;
          #pragma unroll
          for (int nt = 0; nt < 4; ++nt) {
            bx0[0][nt] = *(const floatx4*)(rowp[nt] + kb);
            bx1[0][nt] = *(const floatx4*)(rowp[nt] + kb + 4);
          }
        }
        #pragma unroll
        for (int kk = 0; kk < 8; ++kk) {
          const int cb = kk & 1, nx = cb ^ 1;
          if (kk < 7) {
            int kb = wv * 256 + (kk + 1) * 32 + kr;
            #pragma unroll
            for (int nt = 0; nt < 4; ++nt) {
              bx0[nx][nt] = *(const floatx4*)(rowp[nt] + kb);
              bx1[nx][nt] = *(const floatx4*)(rowp[nt] + kb + 4);
            }
          }
          half8 ah0 = *(const half8*)&wlds[wv][kk * 2 + 0][lane][0];
          half8 ah1 = *(const half8*)&wlds[wv][kk * 2 + 1][lane][0];
          half8 al0 = dec8(lw[kk][0], lw[kk][1]);
          half8 al1 = dec8(lw[kk][2], lw[kk][3]);
          #pragma unroll
          for (int nt = 0; nt < 4; ++nt) {
            half8 bh, bl;
            #pragma unroll
            for (int q = 0; q < 4; ++q) {
              float v0 = bx0[cb][nt][q] * msk[nt];
              float v1 = bx1[cb][nt][q] * msk[nt];
              half_t h0 = (half_t)v0, h1v = (half_t)v1;
              bh[q] = h0;     bh[q + 4] = h1v;
              bl[q] = (half_t)((v0 - (float)h0) * 2048.f);
              bl[q + 4] = (half_t)((v1 - (float)h1v) * 2048.f);
            }
            acc_h[0][nt] = __builtin_amdgcn_mfma_f32_16x16x32_f16(ah0, bh, acc_h[0][nt], 0, 0, 0);
            acc_h[1][nt] = __builtin_amdgcn_mfma_f32_16x16x32_f16(ah1, bh, acc_h[1][nt], 0, 0, 0);
            acc_l[0][nt] = __builtin_amdgcn_mfma_f32_16x16x32_f16(ah0, bl, acc_l[0][nt], 0, 0, 0);
            acc_l[0][nt] = __builtin_amdgcn_mfma_f32_16x16x32_f16(al0, bh, acc_l[0][nt], 0, 0, 0);
            acc_l[1][nt] = __builtin_amdgcn_mfma_f32_16x16x32_f16(ah1, bl, acc_l[1][nt], 0, 0, 0);
            acc_l[1][nt] = __builtin_amdgcn_mfma_f32_16x16x32_f16(al1, bh, acc_l[1][nt], 0, 0, 0);
          }
        }
      } else {
        const half_t *abh, *abl;
        int kofs;
        if (wv < 4) {  // layer==1: x-part = h1[t]
          const int s = t & (NSLOT - 1);
          abh = h1h + s * SLOTE; abl = h1l + s * SLOTE;
          kofs = wv * 256;
        } else {       // recurrent: own layer h[t-1]
          const int s = (t - 1) & (NSLOT - 1);
          abh = (layer == 0 ? h1h : h2h) + s * SLOTE;
          abl = (layer == 0 ? h1l : h2l) + s * SLOTE;
          kofs = (wv - 4) * 256;
        }
        half8 bufh[2][4], bufl[2][4];
        {
          int kb = kofs + kr;
          #pragma unroll
          for (int nt = 0; nt < 4; ++nt) {
            bufh[0][nt] = *(const half8*)(abh + (nt * 16 + ln15) * 1024 + kb);
            bufl[0][nt] = *(const half8*)(abl + (nt * 16 + ln15) * 1024 + kb);
          }
        }
        #pragma unroll
        for (int kk = 0; kk < 8; ++kk) {
          const int cb = kk & 1, nx = cb ^ 1;
          if (kk < 7) {
            int kb = kofs + (kk + 1) * 32 + kr;
            #pragma unroll
            for (int nt = 0; nt < 4; ++nt) {
              bufh[nx][nt] = *(const half8*)(abh + (nt * 16 + ln15) * 1024 + kb);
              bufl[nx][nt] = *(const half8*)(abl + (nt * 16 + ln15) * 1024 + kb);
            }
          }
          half8 ah0 = *(const half8*)&wlds[wv][kk * 2 + 0][lane][0];
          half8 ah1 = *(const half8*)&wlds[wv][kk * 2 + 1][lane][0];
          half8 al0 = dec8(lw[kk][0], lw[kk][1]);
          half8 al1 = dec8(lw[kk][2], lw[kk][3]);
          #pragma unroll
          for (int nt = 0; nt < 4; ++nt) {
            half8 bh = bufh[cb][nt], bl = bufl[cb][nt];
            acc_h[0][nt] = __builtin_amdgcn_mfma_f32_16x16x32_f16(ah0, bh, acc_h[0][nt], 0, 0, 0);
            acc_h[1][nt] = __builtin_amdgcn_mfma_f32_16x16x32_f16(ah1, bh, acc_h[1][nt], 0, 0, 0);
            acc_l[0][nt] = __builtin_amdgcn_mfma_f32_16x16x32_f16(ah0, bl, acc_l[0][nt], 0, 0, 0);
            acc_l[0][nt] = __builtin_amdgcn_mfma_f32_16x16x32_f16(al0, bh, acc_l[0][nt], 0, 0, 0);
            acc_l[1][nt] = __builtin_amdgcn_mfma_f32_16x16x32_f16(ah1, bl, acc_l[1][nt], 0, 0, 0);
            acc_l[1][nt] = __builtin_amdgcn_mfma_f32_16x16x32_f16(al1, bh, acc_l[1][nt], 0, 0, 0);
          }
        }
      }
    }
    // staggered 2-array reduce: waves 0-3 -> part[0], waves 4-7 -> part[1]
    if (!skipH) {
      #pragma unroll
      for (int mt = 0; mt < 2; ++mt)
        #pragma unroll
        for (int idx = 0; idx < 4; ++idx) {
          int nt = (idx + wv) & 3;
          #pragma unroll
          for (int q = 0; q < 4; ++q)
            atomicAdd(&part[wv >> 2][mt * 16 + (lane >> 4) * 4 + q][nt * 16 + ln15],
                      acc_h[mt][nt][q] + INV2048 * acc_l[mt][nt][q]);
        }
    }
    __syncthreads();
    {
      int u = tid & 7, n = tid >> 3;
      float s0 = part[0][u][n]      + part[1][u][n]      + bsum[0];
      float s1 = part[0][8 + u][n]  + part[1][8 + u][n]  + bsum[1];
      float s2 = part[0][16 + u][n] + part[1][16 + u][n] + bsum[2];
      float s3 = part[0][24 + u][n] + part[1][24 + u][n] + bsum[3];
      float is = sigm(s0), fs = sigm(s1), gt = tanh_f(s2), os = sigm(s3);
      c = fs * c + is * gt;
      float h = os * tanh_f(c);
      half_t hhi = (half_t)h;
      half_t hlo = (half_t)((h - (float)hhi) * 2048.f);
      const int ws_ = t & (NSLOT - 1);
      half_t* hbh = (layer == 0 ? h1h : h2h) + ws_ * SLOTE;
      half_t* hbl = (layer == 0 ? h1l : h2l) + ws_ * SLOTE;
      __hip_atomic_store((unsigned short*)&hbh[n * 1024 + wg * 8 + u],
                         __builtin_bit_cast(unsigned short, hhi),
                         __ATOMIC_RELAXED, __HIP_MEMORY_SCOPE_AGENT);
      __hip_atomic_store((unsigned short*)&hbl[n * 1024 + wg * 8 + u],
                         __builtin_bit_cast(unsigned short, hlo),
                         __ATOMIC_RELAXED, __HIP_MEMORY_SCOPE_AGENT);
      if (layer == 1)
        __builtin_nontemporal_store(h, &out[((long)t * 64 + n) * 1024 + wg * 8 + u]);
    }
    __syncthreads();  // every wave drains its own vmcnt before the count
    if (tid == 0) {
      asm volatile("s_waitcnt vmcnt(0)" ::: "memory");
      const int g = wg >> 4;  // 8 groups x 16 WGs
      int* sub = (layer == 0 ? sub1 : sub2);
      int a = __hip_atomic_fetch_add(&sub[(t * 8 + g) * 16], 1,
                                     __ATOMIC_RELAXED, __HIP_MEMORY_SCOPE_AGENT);
      if (a == 15) {
        int* mst = (layer == 0 ? mst1 : mst2);
        int m = __hip_atomic_fetch_add(&mst[t * 16], 1,
                                       __ATOMIC_RELAXED, __HIP_MEMORY_SCOPE_AGENT);
        if (m == 7)
          __hip_atomic_store((layer == 0 ? done1 : done2), t + 1,
                             __ATOMIC_RELAXED, __HIP_MEMORY_SCOPE_AGENT);
      }
    }
    if ((t & 7) == 7)  // periodic L2 invalidate: bounds ring staleness
      __builtin_amdgcn_fence(__ATOMIC_ACQUIRE, "agent");
  }
}

extern "C" void kernel_launch(void* const* d_in, const int* in_sizes, int n_in,
                              void* d_out, int out_size, void* d_ws, size_t ws_size,
                              hipStream_t stream) {
  const int*   tokens = (const int*)d_in[0];
  const float* emb    = (const float*)d_in[1];
  const float* Wih    = (const float*)d_in[2];
  const float* Whh    = (const float*)d_in[3];
  const float* bih    = (const float*)d_in[4];
  const float* bhh    = (const float*)d_in[5];
  float* out = (float*)d_out;

  half_t* whi = (half_t*)d_ws;                            // 32 MB
  uchar*  wlo = (uchar*)((char*)d_ws + 33554432);         // 16 MB
  half_t* h1h = (half_t*)((char*)d_ws + 50331648);        // 4 MB (32 slots)
  half_t* h1l = (half_t*)((char*)d_ws + 54525952);        // 4 MB
  half_t* h2h = (half_t*)((char*)d_ws + 58720256);        // 4 MB
  half_t* h2l = (half_t*)((char*)d_ws + 62914560);        // 4 MB
  int* flagblk = (int*)((char*)d_ws + 67108864);          // ~590 KB

  hipLaunchKernelGGL(conv_w, dim3(65536), dim3(256), 0, stream, Wih, Whh, whi, wlo);
  hipMemsetAsync(flagblk, 0, 663552, stream);

  void* args[] = {(void*)&tokens, (void*)&emb, (void*)&bih, (void*)&bhh,
                  (void*)&whi, (void*)&wlo, (void*)&h1h, (void*)&h1l,
                  (void*)&h2h, (void*)&h2l, (void*)&flagblk, (void*)&out};
  hipError_t e = hipLaunchCooperativeKernel((const void*)lstm_main, dim3(256), dim3(512),
                                            args, 0, stream);
  if (e != hipSuccess) {
    hipMemsetAsync(d_out, 0x43, (size_t)out_size * 4, stream);
  }
}

// Round 13
// 18145.021 us; speedup vs baseline: 4.2164x; 1.1719x over previous
//
#include <hip/hip_runtime.h>

typedef _Float16 half_t;
typedef _Float16 half8 __attribute__((ext_vector_type(8)));
typedef float floatx4 __attribute__((ext_vector_type(4)));
typedef int int4v __attribute__((ext_vector_type(4)));
typedef unsigned uint4v __attribute__((ext_vector_type(4)));
typedef unsigned char uchar;

#define NSTEP 512
#define INV2048 (1.0f / 2048.0f)
#define NSLOT 64
#define SLOTE 65536  // 64 batch x 1024 units per ring slot (f16)

// ---- e5m2 codec: encode = f16 top byte (w/ rounding); decode = byte<<8 ----
__device__ __forceinline__ uchar enc_e5m2(float x) {
  half_t h = (half_t)x;
  unsigned b = (unsigned)__builtin_bit_cast(unsigned short, h);
  return (uchar)(((b + 0x80u) >> 8) & 0xffu);
}

__device__ __forceinline__ half8 dec8(unsigned w0, unsigned w1) {
  uint4v u;
  u[0] = ((w0 & 0x000000ffu) << 8) | ((w0 & 0x0000ff00u) << 16);
  u[1] = ((w0 & 0x00ff0000u) >> 8) | (w0 & 0xff000000u);
  u[2] = ((w1 & 0x000000ffu) << 8) | ((w1 & 0x0000ff00u) << 16);
  u[3] = ((w1 & 0x00ff0000u) >> 8) | (w1 & 0xff000000u);
  return __builtin_bit_cast(half8, u);
}

// hi blob: [layer(2)][wg(128)][wv(8)][frag(16)][lane(64)][i(8)] f16 (32 MB)
// lo blob: same index space, e5m2 of (v-hi)*2048 (16 MB)
__global__ void conv_w(const float* __restrict__ Wih, const float* __restrict__ Whh,
                       half_t* __restrict__ whi, uchar* __restrict__ wlo) {
  long e = (long)blockIdx.x * 256 + threadIdx.x;  // 2^24
  int i    = (int)(e & 7);
  int lane = (int)((e >> 3) & 63);
  int frag = (int)((e >> 9) & 15);
  int wv   = (int)((e >> 13) & 7);
  int wg   = (int)((e >> 16) & 127);
  int layer = (int)((e >> 23) & 1);
  int mt = frag & 1, kk = frag >> 1;
  int mloc = mt * 16 + (lane & 15);
  int grow = (mloc >> 3) * 1024 + wg * 8 + (mloc & 7);
  int k = wv * 256 + kk * 32 + ((lane >> 4) * 8) + i;
  long base = ((long)layer << 22) + (long)grow * 1024;
  float v = (k < 1024) ? Wih[base + k] : Whh[base + (k - 1024)];
  half_t hi = (half_t)v;
  whi[e] = hi;
  wlo[e] = enc_e5m2((v - (float)hi) * 2048.0f);
}

__device__ __forceinline__ float sigm(float x) { return 1.f / (1.f + __expf(-x)); }
__device__ __forceinline__ float tanh_f(float x) {
  x = fminf(15.f, fmaxf(-15.f, x));
  float e = __expf(-2.f * x);
  return (1.f - e) / (1.f + e);
}

__device__ __forceinline__ int ldflag(const int* p) {
  return __hip_atomic_load(p, __ATOMIC_RELAXED, __HIP_MEMORY_SCOPE_AGENT);
}

// 256 WGs x 512 thr. WGs [0,128): layer 0; [128,256): layer 1. Layers decoupled via
// per-layer per-step counters. L0 t waits: done1>=t && done2>=t-48 (ring reuse).
// L1 t waits: done1>=t+1 (h1[t]) && done2>=t.
// h rings: 64 slots x f16 (no lo residual - act quantized to f16; weight split keeps
// gate precision). relaxed-agent stores, plain cached reads of fresh addresses,
// acquire-fence every 16 own-steps (reuse distance 64 -> >=3 fences between).
__launch_bounds__(512, 1)
__global__ void lstm_main(const int* __restrict__ tokens, const float* __restrict__ emb,
                          const float* __restrict__ bih, const float* __restrict__ bhh,
                          const half_t* __restrict__ whi, const uchar* __restrict__ wlo,
                          half_t* __restrict__ h1h, half_t* __restrict__ h2h,
                          int* __restrict__ flagblk, float* __restrict__ out) {
  __shared__ half_t wlds[8][16][64][8];  // 128 KB
  __shared__ float part[2][32][68];      // 17.4 KB
  const int wgid = blockIdx.x;
  const int layer = wgid >> 7;
  const int wg = wgid & 127;
  const int tid = (int)threadIdx.x;
  const int wv = tid >> 6;
  const int lane = tid & 63;
  const int ln15 = lane & 15;
  const int kr = (lane >> 4) * 8;

  int* sub1  = flagblk;             // [512][8] stride 16
  int* sub2  = flagblk + 65536;
  int* mst1  = flagblk + 131072;    // [512] stride 16
  int* mst2  = flagblk + 139264;
  int* done1 = flagblk + 147456;
  int* done2 = flagblk + 147472;

  {  // stage hi weights: 128 KB global -> LDS, once
    const int4v* src = (const int4v*)(whi + (((long)(layer * 128 + wg)) << 16));
    int4v* dst = (int4v*)&wlds[0][0][0][0];
    #pragma unroll
    for (int it = 0; it < 16; ++it) dst[it * 512 + tid] = src[it * 512 + tid];
  }
  const uchar* lobw = wlo + (((long)(layer * 128 + wg)) << 16) + wv * 8192;

  float bsum[4];
  {
    int u = tid & 7;
    for (int g = 0; g < 4; ++g) {
      int bi = layer * 4096 + g * 1024 + wg * 8 + u;
      bsum[g] = bih[bi] + bhh[bi];
    }
  }
  float c = 0.f;
  __syncthreads();

  for (int t = 0; t < NSTEP; ++t) {
    if (tid == 0) {
      const int n1 = (layer == 0) ? t : t + 1;
      const int n2 = (layer == 0) ? t - 48 : t;
      while (ldflag(done1) < n1) __builtin_amdgcn_s_sleep(4);
      while (ldflag(done2) < n2) __builtin_amdgcn_s_sleep(4);
    }
    __syncthreads();
    for (int z = tid; z < 2 * 32 * 68; z += 512) ((float*)part)[z] = 0.f;
    __syncthreads();

    floatx4 zero = {0.f, 0.f, 0.f, 0.f};
    floatx4 acc_h[2][4], acc_l[2][4];
    for (int a = 0; a < 2; ++a)
      for (int b = 0; b < 4; ++b) { acc_h[a][b] = zero; acc_l[a][b] = zero; }

    const bool skipH = (wv >= 4) && (t == 0);
    if (!skipH) {
      // preload e5m2 lo-weight words for all 8 kk (L2-resident)
      unsigned lw[8][4];
      #pragma unroll
      for (int kk = 0; kk < 8; ++kk) {
        const unsigned* l0 = (const unsigned*)(lobw + ((kk * 2 + 0) << 9) + lane * 8);
        const unsigned* l1 = (const unsigned*)(lobw + ((kk * 2 + 1) << 9) + lane * 8);
        lw[kk][0] = l0[0]; lw[kk][1] = l0[1];
        lw[kk][2] = l1[0]; lw[kk][3] = l1[1];
      }

      if (layer == 0 && wv < 4) {
        // x-part from f32 embedding (token 0 -> zero row), full hi/lo split (free)
        int tk[4]; const float* rowp[4]; float msk[4];
        #pragma unroll
        for (int nt = 0; nt < 4; ++nt) {
          tk[nt] = tokens[t * 64 + nt * 16 + ln15];
          rowp[nt] = emb + (long)tk[nt] * 1024;
          msk[nt] = (tk[nt] == 0) ? 0.f : 1.f;
        }
        floatx4 bx0[2][4], bx1[2][4];
        {
          int kb = wv * 256 + kr;
          #pragma unroll
          for (int nt = 0; nt < 4; ++nt) {
            bx0[0][nt] = *(const floatx4*)(rowp[nt] + kb);
            bx1[0][nt] = *(const floatx4*)(rowp[nt] + kb + 4);
          }
        }
        #pragma unroll
        for (int kk = 0; kk < 8; ++kk) {
          const int cb = kk & 1, nx = cb ^ 1;
          if (kk < 7) {
            int kb = wv * 256 + (kk + 1) * 32 + kr;
            #pragma unroll
            for (int nt = 0; nt < 4; ++nt) {
              bx0[nx][nt] = *(const floatx4*)(rowp[nt] + kb);
              bx1[nx][nt] = *(const floatx4*)(rowp[nt] + kb + 4);
            }
          }
          half8 ah0 = *(const half8*)&wlds[wv][kk * 2 + 0][lane][0];
          half8 ah1 = *(const half8*)&wlds[wv][kk * 2 + 1][lane][0];
          half8 al0 = dec8(lw[kk][0], lw[kk][1]);
          half8 al1 = dec8(lw[kk][2], lw[kk][3]);
          #pragma unroll
          for (int nt = 0; nt < 4; ++nt) {
            half8 bh, bl;
            #pragma unroll
            for (int q = 0; q < 4; ++q) {
              float v0 = bx0[cb][nt][q] * msk[nt];
              float v1 = bx1[cb][nt][q] * msk[nt];
              half_t h0 = (half_t)v0, h1v = (half_t)v1;
              bh[q] = h0;     bh[q + 4] = h1v;
              bl[q] = (half_t)((v0 - (float)h0) * 2048.f);
              bl[q + 4] = (half_t)((v1 - (float)h1v) * 2048.f);
            }
            acc_h[0][nt] = __builtin_amdgcn_mfma_f32_16x16x32_f16(ah0, bh, acc_h[0][nt], 0, 0, 0);
            acc_h[1][nt] = __builtin_amdgcn_mfma_f32_16x16x32_f16(ah1, bh, acc_h[1][nt], 0, 0, 0);
            acc_l[0][nt] = __builtin_amdgcn_mfma_f32_16x16x32_f16(ah0, bl, acc_l[0][nt], 0, 0, 0);
            acc_l[0][nt] = __builtin_amdgcn_mfma_f32_16x16x32_f16(al0, bh, acc_l[0][nt], 0, 0, 0);
            acc_l[1][nt] = __builtin_amdgcn_mfma_f32_16x16x32_f16(ah1, bl, acc_l[1][nt], 0, 0, 0);
            acc_l[1][nt] = __builtin_amdgcn_mfma_f32_16x16x32_f16(al1, bh, acc_l[1][nt], 0, 0, 0);
          }
        }
      } else {
        // f16-only activation path (h1 or h2 ring)
        const half_t* abh;
        int kofs;
        if (wv < 4) {  // layer==1: x-part = h1[t]
          abh = h1h + (long)(t & (NSLOT - 1)) * SLOTE;
          kofs = wv * 256;
        } else {       // recurrent: own layer h[t-1]
          abh = (layer == 0 ? h1h : h2h) + (long)((t - 1) & (NSLOT - 1)) * SLOTE;
          kofs = (wv - 4) * 256;
        }
        half8 bufh[2][4];
        {
          int kb = kofs + kr;
          #pragma unroll
          for (int nt = 0; nt < 4; ++nt)
            bufh[0][nt] = *(const half8*)(abh + (nt * 16 + ln15) * 1024 + kb);
        }
        #pragma unroll
        for (int kk = 0; kk < 8; ++kk) {
          const int cb = kk & 1, nx = cb ^ 1;
          if (kk < 7) {
            int kb = kofs + (kk + 1) * 32 + kr;
            #pragma unroll
            for (int nt = 0; nt < 4; ++nt)
              bufh[nx][nt] = *(const half8*)(abh + (nt * 16 + ln15) * 1024 + kb);
          }
          half8 ah0 = *(const half8*)&wlds[wv][kk * 2 + 0][lane][0];
          half8 ah1 = *(const half8*)&wlds[wv][kk * 2 + 1][lane][0];
          half8 al0 = dec8(lw[kk][0], lw[kk][1]);
          half8 al1 = dec8(lw[kk][2], lw[kk][3]);
          #pragma unroll
          for (int nt = 0; nt < 4; ++nt) {
            half8 bh = bufh[cb][nt];
            acc_h[0][nt] = __builtin_amdgcn_mfma_f32_16x16x32_f16(ah0, bh, acc_h[0][nt], 0, 0, 0);
            acc_h[1][nt] = __builtin_amdgcn_mfma_f32_16x16x32_f16(ah1, bh, acc_h[1][nt], 0, 0, 0);
            acc_l[0][nt] = __builtin_amdgcn_mfma_f32_16x16x32_f16(al0, bh, acc_l[0][nt], 0, 0, 0);
            acc_l[1][nt] = __builtin_amdgcn_mfma_f32_16x16x32_f16(al1, bh, acc_l[1][nt], 0, 0, 0);
          }
        }
      }
      // staggered 2-array reduce: waves 0-3 -> part[0], waves 4-7 -> part[1]
      #pragma unroll
      for (int mt = 0; mt < 2; ++mt)
        #pragma unroll
        for (int idx = 0; idx < 4; ++idx) {
          int nt = (idx + wv) & 3;
          #pragma unroll
          for (int q = 0; q < 4; ++q)
            atomicAdd(&part[wv >> 2][mt * 16 + (lane >> 4) * 4 + q][nt * 16 + ln15],
                      acc_h[mt][nt][q] + INV2048 * acc_l[mt][nt][q]);
        }
    }
    __syncthreads();
    {
      int u = tid & 7, n = tid >> 3;
      float s0 = part[0][u][n]      + part[1][u][n]      + bsum[0];
      float s1 = part[0][8 + u][n]  + part[1][8 + u][n]  + bsum[1];
      float s2 = part[0][16 + u][n] + part[1][16 + u][n] + bsum[2];
      float s3 = part[0][24 + u][n] + part[1][24 + u][n] + bsum[3];
      float is = sigm(s0), fs = sigm(s1), gt = tanh_f(s2), os = sigm(s3);
      c = fs * c + is * gt;
      float h = os * tanh_f(c);
      half_t hhi = (half_t)h;
      half_t* hb = (layer == 0 ? h1h : h2h) + (long)(t & (NSLOT - 1)) * SLOTE;
      __hip_atomic_store((unsigned short*)&hb[n * 1024 + wg * 8 + u],
                         __builtin_bit_cast(unsigned short, hhi),
                         __ATOMIC_RELAXED, __HIP_MEMORY_SCOPE_AGENT);
      if (layer == 1)
        __builtin_nontemporal_store(h, &out[((long)t * 64 + n) * 1024 + wg * 8 + u]);
    }
    __syncthreads();  // every wave drains its own vmcnt before the count
    if (tid == 0) {
      asm volatile("s_waitcnt vmcnt(0)" ::: "memory");
      const int g = wg >> 4;  // 8 groups x 16 WGs
      int* sub = (layer == 0 ? sub1 : sub2);
      int a = __hip_atomic_fetch_add(&sub[(t * 8 + g) * 16], 1,
                                     __ATOMIC_RELAXED, __HIP_MEMORY_SCOPE_AGENT);
      if (a == 15) {
        int* mst = (layer == 0 ? mst1 : mst2);
        int m = __hip_atomic_fetch_add(&mst[t * 16], 1,
                                       __ATOMIC_RELAXED, __HIP_MEMORY_SCOPE_AGENT);
        if (m == 7)
          __hip_atomic_store((layer == 0 ? done1 : done2), t + 1,
                             __ATOMIC_RELAXED, __HIP_MEMORY_SCOPE_AGENT);
      }
    }
    if ((t & 15) == 15)  // periodic L2 invalidate: bounds ring staleness (16 << 64)
      __builtin_amdgcn_fence(__ATOMIC_ACQUIRE, "agent");
  }
}

extern "C" void kernel_launch(void* const* d_in, const int* in_sizes, int n_in,
                              void* d_out, int out_size, void* d_ws, size_t ws_size,
                              hipStream_t stream) {
  const int*   tokens = (const int*)d_in[0];
  const float* emb    = (const float*)d_in[1];
  const float* Wih    = (const float*)d_in[2];
  const float* Whh    = (const float*)d_in[3];
  const float* bih    = (const float*)d_in[4];
  const float* bhh    = (const float*)d_in[5];
  float* out = (float*)d_out;

  half_t* whi = (half_t*)d_ws;                            // 32 MB
  uchar*  wlo = (uchar*)((char*)d_ws + 33554432);         // 16 MB
  half_t* h1h = (half_t*)((char*)d_ws + 50331648);        // 8 MB (64 slots f16)
  half_t* h2h = (half_t*)((char*)d_ws + 58720256);        // 8 MB
  int* flagblk = (int*)((char*)d_ws + 67108864);          // ~590 KB

  hipLaunchKernelGGL(conv_w, dim3(65536), dim3(256), 0, stream, Wih, Whh, whi, wlo);
  hipMemsetAsync(flagblk, 0, 663552, stream);

  void* args[] = {(void*)&tokens, (void*)&emb, (void*)&bih, (void*)&bhh,
                  (void*)&whi, (void*)&wlo, (void*)&h1h, (void*)&h2h,
                  (void*)&flagblk, (void*)&out};
  hipError_t e = hipLaunchCooperativeKernel((const void*)lstm_main, dim3(256), dim3(512),
                                            args, 0, stream);
  if (e != hipSuccess) {
    hipMemsetAsync(d_out, 0x43, (size_t)out_size * 4, stream);
  }
}

// Round 14
// 16445.323 us; speedup vs baseline: 4.6522x; 1.1034x over previous
//
#include <hip/hip_runtime.h>

typedef _Float16 half_t;
typedef _Float16 half8 __attribute__((ext_vector_type(8)));
typedef float floatx4 __attribute__((ext_vector_type(4)));
typedef int int4v __attribute__((ext_vector_type(4)));
typedef unsigned uint4v __attribute__((ext_vector_type(4)));
typedef unsigned char uchar;

#define NSTEP 512
#define INV2048 (1.0f / 2048.0f)
#define NSLOT 64
#define SLOTE 65536  // 64 batch x 1024 units per ring slot (f16)

// ---- e5m2 codec: encode = f16 top byte (w/ rounding); decode = byte<<8 ----
__device__ __forceinline__ uchar enc_e5m2(float x) {
  half_t h = (half_t)x;
  unsigned b = (unsigned)__builtin_bit_cast(unsigned short, h);
  return (uchar)(((b + 0x80u) >> 8) & 0xffu);
}

__device__ __forceinline__ half8 dec8(unsigned w0, unsigned w1) {
  uint4v u;
  u[0] = ((w0 & 0x000000ffu) << 8) | ((w0 & 0x0000ff00u) << 16);
  u[1] = ((w0 & 0x00ff0000u) >> 8) | (w0 & 0xff000000u);
  u[2] = ((w1 & 0x000000ffu) << 8) | ((w1 & 0x0000ff00u) << 16);
  u[3] = ((w1 & 0x00ff0000u) >> 8) | (w1 & 0xff000000u);
  return __builtin_bit_cast(half8, u);
}

// hi blob: [layer(2)][wg(128)][wv(8)][frag(16)][lane(64)][i(8)] f16 (32 MB)
// lo blob: same index space, e5m2 of (v-hi)*2048 (16 MB)
__global__ void conv_w(const float* __restrict__ Wih, const float* __restrict__ Whh,
                       half_t* __restrict__ whi, uchar* __restrict__ wlo) {
  long e = (long)blockIdx.x * 256 + threadIdx.x;  // 2^24
  int i    = (int)(e & 7);
  int lane = (int)((e >> 3) & 63);
  int frag = (int)((e >> 9) & 15);
  int wv   = (int)((e >> 13) & 7);
  int wg   = (int)((e >> 16) & 127);
  int layer = (int)((e >> 23) & 1);
  int mt = frag & 1, kk = frag >> 1;
  int mloc = mt * 16 + (lane & 15);
  int grow = (mloc >> 3) * 1024 + wg * 8 + (mloc & 7);
  int k = wv * 256 + kk * 32 + ((lane >> 4) * 8) + i;
  long base = ((long)layer << 22) + (long)grow * 1024;
  float v = (k < 1024) ? Wih[base + k] : Whh[base + (k - 1024)];
  half_t hi = (half_t)v;
  whi[e] = hi;
  wlo[e] = enc_e5m2((v - (float)hi) * 2048.0f);
}

__device__ __forceinline__ float sigm(float x) { return 1.f / (1.f + __expf(-x)); }
__device__ __forceinline__ float tanh_f(float x) {
  x = fminf(15.f, fmaxf(-15.f, x));
  float e = __expf(-2.f * x);
  return (1.f - e) / (1.f + e);
}

__device__ __forceinline__ int ldflag(const int* p) {
  return __hip_atomic_load(p, __ATOMIC_RELAXED, __HIP_MEMORY_SCOPE_AGENT);
}

// 256 WGs x 512 thr. WGs [0,128): layer 0; [128,256): layer 1. Decoupled layers via
// per-layer per-step counters. L0 t waits done1>=t && done2>=t-48; L1 t waits
// done1>=t+1 && done2>=t. h rings 64 slots f16; x and h consumed f16-only (weight
// hi/lo split carries the precision). e5m2 lo-weights live in 32 VGPRs for the whole
// kernel (loaded once). Acquire-fence every 32 own-steps (ring reuse 64 -> >=2
// invalidates inside any stale window).
__launch_bounds__(512, 1)
__global__ void lstm_main(const int* __restrict__ tokens, const float* __restrict__ emb,
                          const float* __restrict__ bih, const float* __restrict__ bhh,
                          const half_t* __restrict__ whi, const uchar* __restrict__ wlo,
                          half_t* __restrict__ h1h, half_t* __restrict__ h2h,
                          int* __restrict__ flagblk, float* __restrict__ out) {
  __shared__ half_t wlds[8][16][64][8];  // 128 KB
  __shared__ float part[2][32][68];      // 17.4 KB
  const int wgid = blockIdx.x;
  const int layer = wgid >> 7;
  const int wg = wgid & 127;
  const int tid = (int)threadIdx.x;
  const int wv = tid >> 6;
  const int lane = tid & 63;
  const int ln15 = lane & 15;
  const int kr = (lane >> 4) * 8;

  int* sub1  = flagblk;             // [512][8] stride 16
  int* sub2  = flagblk + 65536;
  int* mst1  = flagblk + 131072;    // [512] stride 16
  int* mst2  = flagblk + 139264;
  int* done1 = flagblk + 147456;
  int* done2 = flagblk + 147472;

  {  // stage hi weights: 128 KB global -> LDS, once
    const int4v* src = (const int4v*)(whi + (((long)(layer * 128 + wg)) << 16));
    int4v* dst = (int4v*)&wlds[0][0][0][0];
    #pragma unroll
    for (int it = 0; it < 16; ++it) dst[it * 512 + tid] = src[it * 512 + tid];
  }

  // e5m2 lo-weights -> 32 persistent VGPRs (step-invariant)
  unsigned lw[8][4];
  {
    const uchar* lobw = wlo + (((long)(layer * 128 + wg)) << 16) + wv * 8192;
    #pragma unroll
    for (int kk = 0; kk < 8; ++kk) {
      const unsigned* l0 = (const unsigned*)(lobw + ((kk * 2 + 0) << 9) + lane * 8);
      const unsigned* l1 = (const unsigned*)(lobw + ((kk * 2 + 1) << 9) + lane * 8);
      lw[kk][0] = l0[0]; lw[kk][1] = l0[1];
      lw[kk][2] = l1[0]; lw[kk][3] = l1[1];
    }
  }

  float bsum[4];
  {
    int u = tid & 7;
    for (int g = 0; g < 4; ++g) {
      int bi = layer * 4096 + g * 1024 + wg * 8 + u;
      bsum[g] = bih[bi] + bhh[bi];
    }
  }
  float c = 0.f;
  __syncthreads();

  for (int t = 0; t < NSTEP; ++t) {
    if (tid == 0) {
      const int n1 = (layer == 0) ? t : t + 1;
      const int n2 = (layer == 0) ? t - 48 : t;
      while (ldflag(done1) < n1) __builtin_amdgcn_s_sleep(4);
      while (ldflag(done2) < n2) __builtin_amdgcn_s_sleep(4);
    }
    __syncthreads();
    for (int z = tid; z < 2 * 32 * 68; z += 512) ((float*)part)[z] = 0.f;
    __syncthreads();

    floatx4 zero = {0.f, 0.f, 0.f, 0.f};
    floatx4 acc_h[2][4], acc_l[2][4];
    for (int a = 0; a < 2; ++a)
      for (int b = 0; b < 4; ++b) { acc_h[a][b] = zero; acc_l[a][b] = zero; }

    const bool skipH = (wv >= 4) && (t == 0);
    if (!skipH) {
      if (layer == 0 && wv < 4) {
        // x-part from f32 embedding (token 0 -> zero row), f16-only conversion
        int tk[4]; const float* rowp[4]; float msk[4];
        #pragma unroll
        for (int nt = 0; nt < 4; ++nt) {
          tk[nt] = tokens[t * 64 + nt * 16 + ln15];
          rowp[nt] = emb + (long)tk[nt] * 1024;
          msk[nt] = (tk[nt] == 0) ? 0.f : 1.f;
        }
        floatx4 bx0[2][4], bx1[2][4];
        {
          int kb = wv * 256 + kr;
          #pragma unroll
          for (int nt = 0; nt < 4; ++nt) {
            bx0[0][nt] = *(const floatx4*)(rowp[nt] + kb);
            bx1[0][nt] = *(const floatx4*)(rowp[nt] + kb + 4);
          }
        }
        #pragma unroll
        for (int kk = 0; kk < 8; ++kk) {
          const int cb = kk & 1, nx = cb ^ 1;
          if (kk < 7) {
            int kb = wv * 256 + (kk + 1) * 32 + kr;
            #pragma unroll
            for (int nt = 0; nt < 4; ++nt) {
              bx0[nx][nt] = *(const floatx4*)(rowp[nt] + kb);
              bx1[nx][nt] = *(const floatx4*)(rowp[nt] + kb + 4);
            }
          }
          half8 ah0 = *(const half8*)&wlds[wv][kk * 2 + 0][lane][0];
          half8 ah1 = *(const half8*)&wlds[wv][kk * 2 + 1][lane][0];
          half8 al0 = dec8(lw[kk][0], lw[kk][1]);
          half8 al1 = dec8(lw[kk][2], lw[kk][3]);
          #pragma unroll
          for (int nt = 0; nt < 4; ++nt) {
            half8 bh;
            #pragma unroll
            for (int q = 0; q < 4; ++q) {
              bh[q]     = (half_t)(bx0[cb][nt][q] * msk[nt]);
              bh[q + 4] = (half_t)(bx1[cb][nt][q] * msk[nt]);
            }
            acc_h[0][nt] = __builtin_amdgcn_mfma_f32_16x16x32_f16(ah0, bh, acc_h[0][nt], 0, 0, 0);
            acc_h[1][nt] = __builtin_amdgcn_mfma_f32_16x16x32_f16(ah1, bh, acc_h[1][nt], 0, 0, 0);
            acc_l[0][nt] = __builtin_amdgcn_mfma_f32_16x16x32_f16(al0, bh, acc_l[0][nt], 0, 0, 0);
            acc_l[1][nt] = __builtin_amdgcn_mfma_f32_16x16x32_f16(al1, bh, acc_l[1][nt], 0, 0, 0);
          }
        }
      } else {
        // f16-only activation path (h1 or h2 ring)
        const half_t* abh;
        int kofs;
        if (wv < 4) {  // layer==1: x-part = h1[t]
          abh = h1h + (long)(t & (NSLOT - 1)) * SLOTE;
          kofs = wv * 256;
        } else {       // recurrent: own layer h[t-1]
          abh = (layer == 0 ? h1h : h2h) + (long)((t - 1) & (NSLOT - 1)) * SLOTE;
          kofs = (wv - 4) * 256;
        }
        half8 bufh[2][4];
        {
          int kb = kofs + kr;
          #pragma unroll
          for (int nt = 0; nt < 4; ++nt)
            bufh[0][nt] = *(const half8*)(abh + (nt * 16 + ln15) * 1024 + kb);
        }
        #pragma unroll
        for (int kk = 0; kk < 8; ++kk) {
          const int cb = kk & 1, nx = cb ^ 1;
          if (kk < 7) {
            int kb = kofs + (kk + 1) * 32 + kr;
            #pragma unroll
            for (int nt = 0; nt < 4; ++nt)
              bufh[nx][nt] = *(const half8*)(abh + (nt * 16 + ln15) * 1024 + kb);
          }
          half8 ah0 = *(const half8*)&wlds[wv][kk * 2 + 0][lane][0];
          half8 ah1 = *(const half8*)&wlds[wv][kk * 2 + 1][lane][0];
          half8 al0 = dec8(lw[kk][0], lw[kk][1]);
          half8 al1 = dec8(lw[kk][2], lw[kk][3]);
          #pragma unroll
          for (int nt = 0; nt < 4; ++nt) {
            half8 bh = bufh[cb][nt];
            acc_h[0][nt] = __builtin_amdgcn_mfma_f32_16x16x32_f16(ah0, bh, acc_h[0][nt], 0, 0, 0);
            acc_h[1][nt] = __builtin_amdgcn_mfma_f32_16x16x32_f16(ah1, bh, acc_h[1][nt], 0, 0, 0);
            acc_l[0][nt] = __builtin_amdgcn_mfma_f32_16x16x32_f16(al0, bh, acc_l[0][nt], 0, 0, 0);
            acc_l[1][nt] = __builtin_amdgcn_mfma_f32_16x16x32_f16(al1, bh, acc_l[1][nt], 0, 0, 0);
          }
        }
      }
      // staggered 2-array reduce: waves 0-3 -> part[0], waves 4-7 -> part[1]
      #pragma unroll
      for (int mt = 0; mt < 2; ++mt)
        #pragma unroll
        for (int idx = 0; idx < 4; ++idx) {
          int nt = (idx + wv) & 3;
          #pragma unroll
          for (int q = 0; q < 4; ++q)
            atomicAdd(&part[wv >> 2][mt * 16 + (lane >> 4) * 4 + q][nt * 16 + ln15],
                      acc_h[mt][nt][q] + INV2048 * acc_l[mt][nt][q]);
        }
    }
    __syncthreads();
    {
      int u = tid & 7, n = tid >> 3;
      float s0 = part[0][u][n]      + part[1][u][n]      + bsum[0];
      float s1 = part[0][8 + u][n]  + part[1][8 + u][n]  + bsum[1];
      float s2 = part[0][16 + u][n] + part[1][16 + u][n] + bsum[2];
      float s3 = part[0][24 + u][n] + part[1][24 + u][n] + bsum[3];
      float is = sigm(s0), fs = sigm(s1), gt = tanh_f(s2), os = sigm(s3);
      c = fs * c + is * gt;
      float h = os * tanh_f(c);
      half_t hhi = (half_t)h;
      half_t* hb = (layer == 0 ? h1h : h2h) + (long)(t & (NSLOT - 1)) * SLOTE;
      __hip_atomic_store((unsigned short*)&hb[n * 1024 + wg * 8 + u],
                         __builtin_bit_cast(unsigned short, hhi),
                         __ATOMIC_RELAXED, __HIP_MEMORY_SCOPE_AGENT);
      if (layer == 1)
        __builtin_nontemporal_store(h, &out[((long)t * 64 + n) * 1024 + wg * 8 + u]);
    }
    __syncthreads();  // every wave drains its own vmcnt before the count
    if (tid == 0) {
      asm volatile("s_waitcnt vmcnt(0)" ::: "memory");
      const int g = wg >> 4;  // 8 groups x 16 WGs
      int* sub = (layer == 0 ? sub1 : sub2);
      int a = __hip_atomic_fetch_add(&sub[(t * 8 + g) * 16], 1,
                                     __ATOMIC_RELAXED, __HIP_MEMORY_SCOPE_AGENT);
      if (a == 15) {
        int* mst = (layer == 0 ? mst1 : mst2);
        int m = __hip_atomic_fetch_add(&mst[t * 16], 1,
                                       __ATOMIC_RELAXED, __HIP_MEMORY_SCOPE_AGENT);
        if (m == 7)
          __hip_atomic_store((layer == 0 ? done1 : done2), t + 1,
                             __ATOMIC_RELAXED, __HIP_MEMORY_SCOPE_AGENT);
      }
    }
    if ((t & 31) == 31)  // periodic L2 invalidate: bounds ring staleness (32 < 64)
      __builtin_amdgcn_fence(__ATOMIC_ACQUIRE, "agent");
  }
}

extern "C" void kernel_launch(void* const* d_in, const int* in_sizes, int n_in,
                              void* d_out, int out_size, void* d_ws, size_t ws_size,
                              hipStream_t stream) {
  const int*   tokens = (const int*)d_in[0];
  const float* emb    = (const float*)d_in[1];
  const float* Wih    = (const float*)d_in[2];
  const float* Whh    = (const float*)d_in[3];
  const float* bih    = (const float*)d_in[4];
  const float* bhh    = (const float*)d_in[5];
  float* out = (float*)d_out;

  half_t* whi = (half_t*)d_ws;                            // 32 MB
  uchar*  wlo = (uchar*)((char*)d_ws + 33554432);         // 16 MB
  half_t* h1h = (half_t*)((char*)d_ws + 50331648);        // 8 MB (64 slots f16)
  half_t* h2h = (half_t*)((char*)d_ws + 58720256);        // 8 MB
  int* flagblk = (int*)((char*)d_ws + 67108864);          // ~590 KB

  hipLaunchKernelGGL(conv_w, dim3(65536), dim3(256), 0, stream, Wih, Whh, whi, wlo);
  hipMemsetAsync(flagblk, 0, 663552, stream);

  void* args[] = {(void*)&tokens, (void*)&emb, (void*)&bih, (void*)&bhh,
                  (void*)&whi, (void*)&wlo, (void*)&h1h, (void*)&h2h,
                  (void*)&flagblk, (void*)&out};
  hipError_t e = hipLaunchCooperativeKernel((const void*)lstm_main, dim3(256), dim3(512),
                                            args, 0, stream);
  if (e != hipSuccess) {
    hipMemsetAsync(d_out, 0x43, (size_t)out_size * 4, stream);
  }
}

// Round 15
// 15907.793 us; speedup vs baseline: 4.8094x; 1.0338x over previous
//
#include <hip/hip_runtime.h>

typedef _Float16 half_t;
typedef _Float16 half8 __attribute__((ext_vector_type(8)));
typedef float floatx4 __attribute__((ext_vector_type(4)));
typedef int int4v __attribute__((ext_vector_type(4)));
typedef unsigned uint4v __attribute__((ext_vector_type(4)));
typedef unsigned char uchar;

#define NSTEP 512
#define INV2048 (1.0f / 2048.0f)
#define NSLOT 64
#define SLOTE 65536  // 64 batch x 1024 units per ring slot (f16)

// ---- e5m2 codec: encode = f16 top byte (w/ rounding); decode = byte<<8 ----
__device__ __forceinline__ uchar enc_e5m2(float x) {
  half_t h = (half_t)x;
  unsigned b = (unsigned)__builtin_bit_cast(unsigned short, h);
  return (uchar)(((b + 0x80u) >> 8) & 0xffu);
}

__device__ __forceinline__ half8 dec8(unsigned w0, unsigned w1) {
  uint4v u;
  u[0] = ((w0 & 0x000000ffu) << 8) | ((w0 & 0x0000ff00u) << 16);
  u[1] = ((w0 & 0x00ff0000u) >> 8) | (w0 & 0xff000000u);
  u[2] = ((w1 & 0x000000ffu) << 8) | ((w1 & 0x0000ff00u) << 16);
  u[3] = ((w1 & 0x00ff0000u) >> 8) | (w1 & 0xff000000u);
  return __builtin_bit_cast(half8, u);
}

// hi blob: [layer(2)][wg(128)][wv(8)][frag(16)][lane(64)][i(8)] f16 (32 MB)
// lo blob: same index space, e5m2 of (v-hi)*2048 (16 MB)
__global__ void conv_w(const float* __restrict__ Wih, const float* __restrict__ Whh,
                       half_t* __restrict__ whi, uchar* __restrict__ wlo) {
  long e = (long)blockIdx.x * 256 + threadIdx.x;  // 2^24
  int i    = (int)(e & 7);
  int lane = (int)((e >> 3) & 63);
  int frag = (int)((e >> 9) & 15);
  int wv   = (int)((e >> 13) & 7);
  int wg   = (int)((e >> 16) & 127);
  int layer = (int)((e >> 23) & 1);
  int mt = frag & 1, kk = frag >> 1;
  int mloc = mt * 16 + (lane & 15);
  int grow = (mloc >> 3) * 1024 + wg * 8 + (mloc & 7);
  int k = wv * 256 + kk * 32 + ((lane >> 4) * 8) + i;
  long base = ((long)layer << 22) + (long)grow * 1024;
  float v = (k < 1024) ? Wih[base + k] : Whh[base + (k - 1024)];
  half_t hi = (half_t)v;
  whi[e] = hi;
  wlo[e] = enc_e5m2((v - (float)hi) * 2048.0f);
}

__device__ __forceinline__ float sigm(float x) { return 1.f / (1.f + __expf(-x)); }
__device__ __forceinline__ float tanh_f(float x) {
  x = fminf(15.f, fmaxf(-15.f, x));
  float e = __expf(-2.f * x);
  return (1.f - e) / (1.f + e);
}

// wave-uniform flag wait (all 64 lanes load same address -> one request/wave)
__device__ __forceinline__ void wwait(const int* p, int n) {
  while (__hip_atomic_load(p, __ATOMIC_RELAXED, __HIP_MEMORY_SCOPE_AGENT) < n)
    __builtin_amdgcn_s_sleep(4);
}

// 256 WGs x 512 thr. WGs [0,128): layer 0; [128,256): layer 1. Decoupled layers.
// PER-WAVE waits: x-waves (wv<4) start immediately (their dep long-satisfied);
// h-waves (wv>=4) carry the recurrent wait -> x work overlaps the critical chain.
// Writes stay gated: the pre-activation __syncthreads can't pass until h-waves wake.
// h rings 64 slots f16; depth-4 pipelined h loads; e5m2 lo-weights in VGPRs;
// acquire-fence every 32 own-steps (ring reuse 64).
__launch_bounds__(512, 1)
__global__ void lstm_main(const int* __restrict__ tokens, const float* __restrict__ emb,
                          const float* __restrict__ bih, const float* __restrict__ bhh,
                          const half_t* __restrict__ whi, const uchar* __restrict__ wlo,
                          half_t* __restrict__ h1h, half_t* __restrict__ h2h,
                          int* __restrict__ flagblk, float* __restrict__ out) {
  __shared__ half_t wlds[8][16][64][8];  // 128 KB
  __shared__ float part[2][32][68];      // 17.4 KB
  const int wgid = blockIdx.x;
  const int layer = wgid >> 7;
  const int wg = wgid & 127;
  const int tid = (int)threadIdx.x;
  const int wv = tid >> 6;
  const int lane = tid & 63;
  const int ln15 = lane & 15;
  const int kr = (lane >> 4) * 8;

  int* sub1  = flagblk;             // [512][8] stride 16
  int* sub2  = flagblk + 65536;
  int* mst1  = flagblk + 131072;    // [512] stride 16
  int* mst2  = flagblk + 139264;
  int* done1 = flagblk + 147456;    // separate cache lines / pages
  int* done2 = flagblk + 147456 + 1024;

  {  // stage hi weights: 128 KB global -> LDS, once
    const int4v* src = (const int4v*)(whi + (((long)(layer * 128 + wg)) << 16));
    int4v* dst = (int4v*)&wlds[0][0][0][0];
    #pragma unroll
    for (int it = 0; it < 16; ++it) dst[it * 512 + tid] = src[it * 512 + tid];
  }

  // e5m2 lo-weights -> 32 persistent VGPRs (step-invariant)
  unsigned lw[8][4];
  {
    const uchar* lobw = wlo + (((long)(layer * 128 + wg)) << 16) + wv * 8192;
    #pragma unroll
    for (int kk = 0; kk < 8; ++kk) {
      const unsigned* l0 = (const unsigned*)(lobw + ((kk * 2 + 0) << 9) + lane * 8);
      const unsigned* l1 = (const unsigned*)(lobw + ((kk * 2 + 1) << 9) + lane * 8);
      lw[kk][0] = l0[0]; lw[kk][1] = l0[1];
      lw[kk][2] = l1[0]; lw[kk][3] = l1[1];
    }
  }

  float bsum[4];
  {
    int u = tid & 7;
    for (int g = 0; g < 4; ++g) {
      int bi = layer * 4096 + g * 1024 + wg * 8 + u;
      bsum[g] = bih[bi] + bhh[bi];
    }
  }
  float c = 0.f;
  __syncthreads();

  for (int t = 0; t < NSTEP; ++t) {
    for (int z = tid; z < 2 * 32 * 68; z += 512) ((float*)part)[z] = 0.f;
    __syncthreads();

    // per-wave dependency waits (x-waves proceed; h-waves carry the recurrence)
    if (layer == 0) {
      if (wv >= 4) {
        if (t > 0) wwait(done1, t);   // own-layer h[t-1]
        wwait(done2, t - 48);         // ring overwrite guard (trivially true t<=48)
      }
    } else {
      if (wv < 4) wwait(done1, t + 1);  // h1[t] (L0 runs ahead: usually no wait)
      else        wwait(done2, t);      // own-layer h[t-1]  (t=0: trivially true)
    }

    floatx4 zero = {0.f, 0.f, 0.f, 0.f};
    floatx4 acc_h[2][4], acc_l[2][4];
    for (int a = 0; a < 2; ++a)
      for (int b = 0; b < 4; ++b) { acc_h[a][b] = zero; acc_l[a][b] = zero; }

    const bool skipH = (wv >= 4) && (t == 0);
    if (!skipH) {
      if (layer == 0 && wv < 4) {
        // x-part from f32 embedding (token 0 -> zero row), f16-only conversion
        int tk[4]; const float* rowp[4]; float msk[4];
        #pragma unroll
        for (int nt = 0; nt < 4; ++nt) {
          tk[nt] = tokens[t * 64 + nt * 16 + ln15];
          rowp[nt] = emb + (long)tk[nt] * 1024;
          msk[nt] = (tk[nt] == 0) ? 0.f : 1.f;
        }
        floatx4 bx0[2][4], bx1[2][4];
        {
          int kb = wv * 256 + kr;
          #pragma unroll
          for (int nt = 0; nt < 4; ++nt) {
            bx0[0][nt] = *(const floatx4*)(rowp[nt] + kb);
            bx1[0][nt] = *(const floatx4*)(rowp[nt] + kb + 4);
          }
        }
        #pragma unroll
        for (int kk = 0; kk < 8; ++kk) {
          const int cb = kk & 1, nx = cb ^ 1;
          if (kk < 7) {
            int kb = wv * 256 + (kk + 1) * 32 + kr;
            #pragma unroll
            for (int nt = 0; nt < 4; ++nt) {
              bx0[nx][nt] = *(const floatx4*)(rowp[nt] + kb);
              bx1[nx][nt] = *(const floatx4*)(rowp[nt] + kb + 4);
            }
          }
          half8 ah0 = *(const half8*)&wlds[wv][kk * 2 + 0][lane][0];
          half8 ah1 = *(const half8*)&wlds[wv][kk * 2 + 1][lane][0];
          half8 al0 = dec8(lw[kk][0], lw[kk][1]);
          half8 al1 = dec8(lw[kk][2], lw[kk][3]);
          #pragma unroll
          for (int nt = 0; nt < 4; ++nt) {
            half8 bh;
            #pragma unroll
            for (int q = 0; q < 4; ++q) {
              bh[q]     = (half_t)(bx0[cb][nt][q] * msk[nt]);
              bh[q + 4] = (half_t)(bx1[cb][nt][q] * msk[nt]);
            }
            acc_h[0][nt] = __builtin_amdgcn_mfma_f32_16x16x32_f16(ah0, bh, acc_h[0][nt], 0, 0, 0);
            acc_h[1][nt] = __builtin_amdgcn_mfma_f32_16x16x32_f16(ah1, bh, acc_h[1][nt], 0, 0, 0);
            acc_l[0][nt] = __builtin_amdgcn_mfma_f32_16x16x32_f16(al0, bh, acc_l[0][nt], 0, 0, 0);
            acc_l[1][nt] = __builtin_amdgcn_mfma_f32_16x16x32_f16(al1, bh, acc_l[1][nt], 0, 0, 0);
          }
        }
      } else {
        // f16 activation path (h1 or h2 ring), depth-4 pipelined loads
        const half_t* abh;
        int kofs;
        if (wv < 4) {  // layer==1: x-part = h1[t]
          abh = h1h + (long)(t & (NSLOT - 1)) * SLOTE;
          kofs = wv * 256;
        } else {       // recurrent: own layer h[t-1]
          abh = (layer == 0 ? h1h : h2h) + (long)((t - 1) & (NSLOT - 1)) * SLOTE;
          kofs = (wv - 4) * 256;
        }
        half8 bufh[4][4];
        #pragma unroll
        for (int pf = 0; pf < 3; ++pf) {
          int kb = kofs + pf * 32 + kr;
          #pragma unroll
          for (int nt = 0; nt < 4; ++nt)
            bufh[pf][nt] = *(const half8*)(abh + (nt * 16 + ln15) * 1024 + kb);
        }
        #pragma unroll
        for (int kk = 0; kk < 8; ++kk) {
          if (kk < 5) {
            int kb = kofs + (kk + 3) * 32 + kr;
            #pragma unroll
            for (int nt = 0; nt < 4; ++nt)
              bufh[(kk + 3) & 3][nt] = *(const half8*)(abh + (nt * 16 + ln15) * 1024 + kb);
          }
          half8 ah0 = *(const half8*)&wlds[wv][kk * 2 + 0][lane][0];
          half8 ah1 = *(const half8*)&wlds[wv][kk * 2 + 1][lane][0];
          half8 al0 = dec8(lw[kk][0], lw[kk][1]);
          half8 al1 = dec8(lw[kk][2], lw[kk][3]);
          #pragma unroll
          for (int nt = 0; nt < 4; ++nt) {
            half8 bh = bufh[kk & 3][nt];
            acc_h[0][nt] = __builtin_amdgcn_mfma_f32_16x16x32_f16(ah0, bh, acc_h[0][nt], 0, 0, 0);
            acc_h[1][nt] = __builtin_amdgcn_mfma_f32_16x16x32_f16(ah1, bh, acc_h[1][nt], 0, 0, 0);
            acc_l[0][nt] = __builtin_amdgcn_mfma_f32_16x16x32_f16(al0, bh, acc_l[0][nt], 0, 0, 0);
            acc_l[1][nt] = __builtin_amdgcn_mfma_f32_16x16x32_f16(al1, bh, acc_l[1][nt], 0, 0, 0);
          }
        }
      }
      // staggered 2-array reduce: waves 0-3 -> part[0], waves 4-7 -> part[1]
      #pragma unroll
      for (int mt = 0; mt < 2; ++mt)
        #pragma unroll
        for (int idx = 0; idx < 4; ++idx) {
          int nt = (idx + wv) & 3;
          #pragma unroll
          for (int q = 0; q < 4; ++q)
            atomicAdd(&part[wv >> 2][mt * 16 + (lane >> 4) * 4 + q][nt * 16 + ln15],
                      acc_h[mt][nt][q] + INV2048 * acc_l[mt][nt][q]);
        }
    }
    __syncthreads();
    {
      int u = tid & 7, n = tid >> 3;
      float s0 = part[0][u][n]      + part[1][u][n]      + bsum[0];
      float s1 = part[0][8 + u][n]  + part[1][8 + u][n]  + bsum[1];
      float s2 = part[0][16 + u][n] + part[1][16 + u][n] + bsum[2];
      float s3 = part[0][24 + u][n] + part[1][24 + u][n] + bsum[3];
      float is = sigm(s0), fs = sigm(s1), gt = tanh_f(s2), os = sigm(s3);
      c = fs * c + is * gt;
      float h = os * tanh_f(c);
      half_t hhi = (half_t)h;
      half_t* hb = (layer == 0 ? h1h : h2h) + (long)(t & (NSLOT - 1)) * SLOTE;
      __hip_atomic_store((unsigned short*)&hb[n * 1024 + wg * 8 + u],
                         __builtin_bit_cast(unsigned short, hhi),
                         __ATOMIC_RELAXED, __HIP_MEMORY_SCOPE_AGENT);
      if (layer == 1)
        __builtin_nontemporal_store(h, &out[((long)t * 64 + n) * 1024 + wg * 8 + u]);
    }
    __syncthreads();  // compiler drains vmcnt before s_barrier -> stores complete
    if (tid == 0) {
      asm volatile("s_waitcnt vmcnt(0)" ::: "memory");
      const int g = wg >> 4;  // 8 groups x 16 WGs
      int* sub = (layer == 0 ? sub1 : sub2);
      int a = __hip_atomic_fetch_add(&sub[(t * 8 + g) * 16], 1,
                                     __ATOMIC_RELAXED, __HIP_MEMORY_SCOPE_AGENT);
      if (a == 15) {
        int* mst = (layer == 0 ? mst1 : mst2);
        int m = __hip_atomic_fetch_add(&mst[t * 16], 1,
                                       __ATOMIC_RELAXED, __HIP_MEMORY_SCOPE_AGENT);
        if (m == 7)
          __hip_atomic_store((layer == 0 ? done1 : done2), t + 1,
                             __ATOMIC_RELAXED, __HIP_MEMORY_SCOPE_AGENT);
      }
    }
    if ((t & 31) == 31)  // periodic L2 invalidate: bounds ring staleness (32 < 64)
      __builtin_amdgcn_fence(__ATOMIC_ACQUIRE, "agent");
  }
}

extern "C" void kernel_launch(void* const* d_in, const int* in_sizes, int n_in,
                              void* d_out, int out_size, void* d_ws, size_t ws_size,
                              hipStream_t stream) {
  const int*   tokens = (const int*)d_in[0];
  const float* emb    = (const float*)d_in[1];
  const float* Wih    = (const float*)d_in[2];
  const float* Whh    = (const float*)d_in[3];
  const float* bih    = (const float*)d_in[4];
  const float* bhh    = (const float*)d_in[5];
  float* out = (float*)d_out;

  half_t* whi = (half_t*)d_ws;                            // 32 MB
  uchar*  wlo = (uchar*)((char*)d_ws + 33554432);         // 16 MB
  half_t* h1h = (half_t*)((char*)d_ws + 50331648);        // 8 MB (64 slots f16)
  half_t* h2h = (half_t*)((char*)d_ws + 58720256);        // 8 MB
  int* flagblk = (int*)((char*)d_ws + 67108864);          // ~600 KB

  hipLaunchKernelGGL(conv_w, dim3(65536), dim3(256), 0, stream, Wih, Whh, whi, wlo);
  hipMemsetAsync(flagblk, 0, 663552, stream);

  void* args[] = {(void*)&tokens, (void*)&emb, (void*)&bih, (void*)&bhh,
                  (void*)&whi, (void*)&wlo, (void*)&h1h, (void*)&h2h,
                  (void*)&flagblk, (void*)&out};
  hipError_t e = hipLaunchCooperativeKernel((const void*)lstm_main, dim3(256), dim3(512),
                                            args, 0, stream);
  if (e != hipSuccess) {
    hipMemsetAsync(d_out, 0x43, (size_t)out_size * 4, stream);
  }
}